// Round 8
// baseline (4266.134 us; speedup 1.0000x reference)
//
#include <hip/hip_runtime.h>
#include <math.h>

// ---------------------------------------------------------------------------
// Variance-propagating UNet (density prop), NHWC.
// Round 7->8: hybrid kept (fp32 vector mu-chain = exact relu gates, bf16
// hi+lo MFMA s-conv). muconv templated on (Cin1,Cin2,Cout) + unroll-2 ci
// loops -> software-pipelined loads to cover L2/L3 latency at the low wave
// counts of the small-spatial layers (D2A was 1.9 waves/SIMD, VALUBusy 23%).
// ---------------------------------------------------------------------------

typedef __attribute__((ext_vector_type(8))) short short8;
typedef __attribute__((ext_vector_type(4))) float floatx4;

__device__ __forceinline__ float softplus_f(float x) { return log1pf(expf(x)); }

__device__ __forceinline__ unsigned short f2bf(float x) {
    unsigned int u = __float_as_uint(x);
    u = (u + 0x7FFF + ((u >> 16) & 1)) >> 16;
    return (unsigned short)u;
}
__device__ __forceinline__ float bfval(unsigned short h) {
    return __uint_as_float((unsigned int)h << 16);
}
__device__ __forceinline__ float bf2f_lo(unsigned int u) {
    return __uint_as_float(u << 16);
}
__device__ __forceinline__ float bf2f_hi(unsigned int u) {
    return __uint_as_float(u & 0xFFFF0000u);
}

// ---- weight prep: wTsq[tap][co][ci] = bf16(w[tap][ci][co]^2)
__global__ void wprep_kernel(const float* __restrict__ w,
                             unsigned short* __restrict__ wTsq,
                             int Cin, int Cout, int n)
{
    int idx = blockIdx.x * blockDim.x + threadIdx.x;
    if (idx >= n) return;
    int per = Cin * Cout;
    int tap = idx / per;
    int rem = idx - tap * per;
    int co = rem / Cin;
    int ci = rem - co * Cin;
    float v = w[(size_t)(tap * Cin + ci) * Cout + co];
    wTsq[idx] = f2bf(v * v);
}

__global__ void sp_kernel(const float* __restrict__ wsig,
                          float* __restrict__ sp, int n)
{
    int i = blockIdx.x * blockDim.x + threadIdx.x;
    if (i < n) sp[i] = softplus_f(wsig[i]);
}

// ---- t from fp32 mu + hi/lo bf16 s (optional 2nd source at crop offset)
__global__ void t_mixed_kernel(const float* __restrict__ mu1,
                               const unsigned short* __restrict__ s1h,
                               const unsigned short* __restrict__ s1l,
                               const float* __restrict__ mu2,
                               const unsigned short* __restrict__ s2h,
                               const unsigned short* __restrict__ s2l,
                               float* __restrict__ t_out,
                               int B_, int Hin, int Win, int Cin1, int Cin2,
                               int H2, int W2, int dh, int dw)
{
    int pix = blockIdx.x * blockDim.x + threadIdx.x;
    int total = B_ * Hin * Win;
    if (pix >= total) return;
    float acc = 0.f;
    {
        const float* mp = mu1 + (size_t)pix * Cin1;
        const unsigned short* sh = s1h + (size_t)pix * Cin1;
        const unsigned short* sl = s1l + (size_t)pix * Cin1;
        for (int ci = 0; ci < Cin1; ci += 8) {
            float4 m0 = *(const float4*)(mp + ci);
            float4 m1 = *(const float4*)(mp + ci + 4);
            uint4 vh = *(const uint4*)(sh + ci);
            uint4 vl = *(const uint4*)(sl + ci);
            acc += m0.x*m0.x + m0.y*m0.y + m0.z*m0.z + m0.w*m0.w
                 + m1.x*m1.x + m1.y*m1.y + m1.z*m1.z + m1.w*m1.w;
            acc += bf2f_lo(vh.x) + bf2f_hi(vh.x) + bf2f_lo(vh.y) + bf2f_hi(vh.y)
                 + bf2f_lo(vh.z) + bf2f_hi(vh.z) + bf2f_lo(vh.w) + bf2f_hi(vh.w);
            acc += bf2f_lo(vl.x) + bf2f_hi(vl.x) + bf2f_lo(vl.y) + bf2f_hi(vl.y)
                 + bf2f_lo(vl.z) + bf2f_hi(vl.z) + bf2f_lo(vl.w) + bf2f_hi(vl.w);
        }
    }
    if (Cin2 > 0) {
        int b = pix / (Hin * Win);
        int rem = pix - b * (Hin * Win);
        int h = rem / Win, w = rem - (rem / Win) * Win;
        size_t base = ((size_t)(b * H2 + h + dh) * W2 + (w + dw)) * Cin2;
        const float* mp = mu2 + base;
        const unsigned short* sh = s2h + base;
        const unsigned short* sl = s2l + base;
        for (int ci = 0; ci < Cin2; ci += 8) {
            float4 m0 = *(const float4*)(mp + ci);
            float4 m1 = *(const float4*)(mp + ci + 4);
            uint4 vh = *(const uint4*)(sh + ci);
            uint4 vl = *(const uint4*)(sl + ci);
            acc += m0.x*m0.x + m0.y*m0.y + m0.z*m0.z + m0.w*m0.w
                 + m1.x*m1.x + m1.y*m1.y + m1.z*m1.z + m1.w*m1.w;
            acc += bf2f_lo(vh.x) + bf2f_hi(vh.x) + bf2f_lo(vh.y) + bf2f_hi(vh.y)
                 + bf2f_lo(vh.z) + bf2f_hi(vh.z) + bf2f_lo(vh.w) + bf2f_hi(vh.w);
            acc += bf2f_lo(vl.x) + bf2f_hi(vl.x) + bf2f_lo(vl.y) + bf2f_hi(vl.y)
                 + bf2f_lo(vl.z) + bf2f_hi(vl.z) + bf2f_lo(vl.w) + bf2f_hi(vl.w);
        }
    }
    t_out[pix] = acc;
}

// ---- t from fp32 mu + fp32 s (for unpool-conv inputs)
__global__ void t_f32_kernel(const float* __restrict__ mu1, const float* __restrict__ s1,
                             float* __restrict__ t_out, int total, int Cin)
{
    int pix = blockIdx.x * blockDim.x + threadIdx.x;
    if (pix >= total) return;
    const float* mp = mu1 + (size_t)pix * Cin;
    const float* sp = s1 + (size_t)pix * Cin;
    float acc = 0.f;
    for (int ci = 0; ci < Cin; ci += 4) {
        float4 m = *(const float4*)(mp + ci);
        float4 s = *(const float4*)(sp + ci);
        acc += m.x * m.x + s.x + m.y * m.y + s.y
             + m.z * m.z + s.z + m.w * m.w + s.w;
    }
    t_out[pix] = acc;
}

// ---- q9: sum t over valid 3x3 taps (pad=1)
__global__ void q9_kernel(const float* __restrict__ t_in,
                          float* __restrict__ q9, int B_, int H, int W)
{
    int pix = blockIdx.x * blockDim.x + threadIdx.x;
    int total = B_ * H * W;
    if (pix >= total) return;
    int b = pix / (H * W);
    int rem = pix - b * (H * W);
    int h = rem / W, w = rem - (rem / W) * W;
    float acc = 0.f;
    for (int kh = 0; kh < 3; kh++) {
        int ih = h + kh - 1;
        if ((unsigned)ih >= (unsigned)H) continue;
        for (int kw = 0; kw < 3; kw++) {
            int iw = w + kw - 1;
            if ((unsigned)iw >= (unsigned)W) continue;
            acc += t_in[(size_t)(b * H + ih) * W + iw];
        }
    }
    q9[pix] = acc;
}

// ---- mu conv (templated): fp32 vector, 8 cout x 2 W-adjacent pixels per
// thread; compile-time Cin/Cout + unroll-2 -> software-pipelined loads.
template<int CIN1, int CIN2, int COUT>
__global__ void __launch_bounds__(256)
muconv_t(const float* __restrict__ mu1, const float* __restrict__ mu2,
         const float* __restrict__ w_mu,
         float* __restrict__ mu_out,
         int B_, int H, int W, int H2, int W2, int dh, int dw)
{
    const int cog = threadIdx.x * 8;
    const int Wp = (W + 1) >> 1;
    int pr = blockIdx.x * blockDim.y + threadIdx.y;
    int totalP = B_ * H * Wp;
    if (pr >= totalP) return;
    int b = pr / (H * Wp);
    int rem = pr - b * (H * Wp);
    int h = rem / Wp;
    int w0 = (rem - h * Wp) << 1;
    const bool pex1 = (w0 + 1) < W;

    float acc0[8], acc1[8];
#pragma unroll
    for (int i = 0; i < 8; i++) { acc0[i] = 0.f; acc1[i] = 0.f; }

    for (int kh = 0; kh < 3; kh++) {
        int ih = h + kh - 1;
        if ((unsigned)ih >= (unsigned)H) continue;
        for (int kw = 0; kw < 3; kw++) {
            int iw0 = w0 + kw - 1;
            int iw1 = iw0 + 1;
            bool v0 = (unsigned)iw0 < (unsigned)W;
            bool v1 = pex1 && ((unsigned)iw1 < (unsigned)W);
            if (!v0 && !v1) continue;
            const int CIN = CIN1 + CIN2;
            const float* __restrict__ wp =
                w_mu + (size_t)((kh * 3 + kw) * CIN) * COUT + cog;
            // ---- source 1 ----
            {
                const float* rowb = mu1 + (size_t)(b * H + ih) * W * CIN1;
                if (v0 && v1) {
                    const float* mp0 = rowb + (size_t)iw0 * CIN1;
                    const float* mp1 = rowb + (size_t)iw1 * CIN1;
#pragma unroll 2
                    for (int ci = 0; ci < CIN1; ci += 4) {
                        const float* wb = wp + (size_t)ci * COUT;
                        float4 a0 = *(const float4*)(wb);
                        float4 a1 = *(const float4*)(wb + 4);
                        float4 b0 = *(const float4*)(wb + COUT);
                        float4 b1 = *(const float4*)(wb + COUT + 4);
                        float4 c0 = *(const float4*)(wb + 2 * COUT);
                        float4 c1 = *(const float4*)(wb + 2 * COUT + 4);
                        float4 d0 = *(const float4*)(wb + 3 * COUT);
                        float4 d1 = *(const float4*)(wb + 3 * COUT + 4);
                        float4 m0 = *(const float4*)(mp0 + ci);
                        float4 m1 = *(const float4*)(mp1 + ci);
                        acc0[0] += m0.x*a0.x + m0.y*b0.x + m0.z*c0.x + m0.w*d0.x;
                        acc0[1] += m0.x*a0.y + m0.y*b0.y + m0.z*c0.y + m0.w*d0.y;
                        acc0[2] += m0.x*a0.z + m0.y*b0.z + m0.z*c0.z + m0.w*d0.z;
                        acc0[3] += m0.x*a0.w + m0.y*b0.w + m0.z*c0.w + m0.w*d0.w;
                        acc0[4] += m0.x*a1.x + m0.y*b1.x + m0.z*c1.x + m0.w*d1.x;
                        acc0[5] += m0.x*a1.y + m0.y*b1.y + m0.z*c1.y + m0.w*d1.y;
                        acc0[6] += m0.x*a1.z + m0.y*b1.z + m0.z*c1.z + m0.w*d1.z;
                        acc0[7] += m0.x*a1.w + m0.y*b1.w + m0.z*c1.w + m0.w*d1.w;
                        acc1[0] += m1.x*a0.x + m1.y*b0.x + m1.z*c0.x + m1.w*d0.x;
                        acc1[1] += m1.x*a0.y + m1.y*b0.y + m1.z*c0.y + m1.w*d0.y;
                        acc1[2] += m1.x*a0.z + m1.y*b0.z + m1.z*c0.z + m1.w*d0.z;
                        acc1[3] += m1.x*a0.w + m1.y*b0.w + m1.z*c0.w + m1.w*d0.w;
                        acc1[4] += m1.x*a1.x + m1.y*b1.x + m1.z*c1.x + m1.w*d1.x;
                        acc1[5] += m1.x*a1.y + m1.y*b1.y + m1.z*c1.y + m1.w*d1.y;
                        acc1[6] += m1.x*a1.z + m1.y*b1.z + m1.z*c1.z + m1.w*d1.z;
                        acc1[7] += m1.x*a1.w + m1.y*b1.w + m1.z*c1.w + m1.w*d1.w;
                    }
                } else {
                    const float* mp = rowb + (size_t)(v0 ? iw0 : iw1) * CIN1;
                    float* ac = v0 ? acc0 : acc1;
#pragma unroll 2
                    for (int ci = 0; ci < CIN1; ci += 4) {
                        const float* wb = wp + (size_t)ci * COUT;
                        float4 a0 = *(const float4*)(wb);
                        float4 a1 = *(const float4*)(wb + 4);
                        float4 b0 = *(const float4*)(wb + COUT);
                        float4 b1 = *(const float4*)(wb + COUT + 4);
                        float4 c0 = *(const float4*)(wb + 2 * COUT);
                        float4 c1 = *(const float4*)(wb + 2 * COUT + 4);
                        float4 d0 = *(const float4*)(wb + 3 * COUT);
                        float4 d1 = *(const float4*)(wb + 3 * COUT + 4);
                        float4 m0 = *(const float4*)(mp + ci);
                        ac[0] += m0.x*a0.x + m0.y*b0.x + m0.z*c0.x + m0.w*d0.x;
                        ac[1] += m0.x*a0.y + m0.y*b0.y + m0.z*c0.y + m0.w*d0.y;
                        ac[2] += m0.x*a0.z + m0.y*b0.z + m0.z*c0.z + m0.w*d0.z;
                        ac[3] += m0.x*a0.w + m0.y*b0.w + m0.z*c0.w + m0.w*d0.w;
                        ac[4] += m0.x*a1.x + m0.y*b1.x + m0.z*c1.x + m0.w*d1.x;
                        ac[5] += m0.x*a1.y + m0.y*b1.y + m0.z*c1.y + m0.w*d1.y;
                        ac[6] += m0.x*a1.z + m0.y*b1.z + m0.z*c1.z + m0.w*d1.z;
                        ac[7] += m0.x*a1.w + m0.y*b1.w + m0.z*c1.w + m0.w*d1.w;
                    }
                }
            }
            // ---- source 2 (fused skip concat, compile-time enabled) ----
            if (CIN2 > 0) {
                const float* rowb = mu2 + (size_t)(b * H2 + ih + dh) * W2 * CIN2;
                const float* __restrict__ wp2 = wp + (size_t)CIN1 * COUT;
                if (v0 && v1) {
                    const float* mp0 = rowb + (size_t)(iw0 + dw) * CIN2;
                    const float* mp1 = rowb + (size_t)(iw1 + dw) * CIN2;
#pragma unroll 2
                    for (int ci = 0; ci < CIN2; ci += 4) {
                        const float* wb = wp2 + (size_t)ci * COUT;
                        float4 a0 = *(const float4*)(wb);
                        float4 a1 = *(const float4*)(wb + 4);
                        float4 b0 = *(const float4*)(wb + COUT);
                        float4 b1 = *(const float4*)(wb + COUT + 4);
                        float4 c0 = *(const float4*)(wb + 2 * COUT);
                        float4 c1 = *(const float4*)(wb + 2 * COUT + 4);
                        float4 d0 = *(const float4*)(wb + 3 * COUT);
                        float4 d1 = *(const float4*)(wb + 3 * COUT + 4);
                        float4 m0 = *(const float4*)(mp0 + ci);
                        float4 m1 = *(const float4*)(mp1 + ci);
                        acc0[0] += m0.x*a0.x + m0.y*b0.x + m0.z*c0.x + m0.w*d0.x;
                        acc0[1] += m0.x*a0.y + m0.y*b0.y + m0.z*c0.y + m0.w*d0.y;
                        acc0[2] += m0.x*a0.z + m0.y*b0.z + m0.z*c0.z + m0.w*d0.z;
                        acc0[3] += m0.x*a0.w + m0.y*b0.w + m0.z*c0.w + m0.w*d0.w;
                        acc0[4] += m0.x*a1.x + m0.y*b1.x + m0.z*c1.x + m0.w*d1.x;
                        acc0[5] += m0.x*a1.y + m0.y*b1.y + m0.z*c1.y + m0.w*d1.y;
                        acc0[6] += m0.x*a1.z + m0.y*b1.z + m0.z*c1.z + m0.w*d1.z;
                        acc0[7] += m0.x*a1.w + m0.y*b1.w + m0.z*c1.w + m0.w*d1.w;
                        acc1[0] += m1.x*a0.x + m1.y*b0.x + m1.z*c0.x + m1.w*d0.x;
                        acc1[1] += m1.x*a0.y + m1.y*b0.y + m1.z*c0.y + m1.w*d0.y;
                        acc1[2] += m1.x*a0.z + m1.y*b0.z + m1.z*c0.z + m1.w*d0.z;
                        acc1[3] += m1.x*a0.w + m1.y*b0.w + m1.z*c0.w + m1.w*d0.w;
                        acc1[4] += m1.x*a1.x + m1.y*b1.x + m1.z*c1.x + m1.w*d1.x;
                        acc1[5] += m1.x*a1.y + m1.y*b1.y + m1.z*c1.y + m1.w*d1.y;
                        acc1[6] += m1.x*a1.z + m1.y*b1.z + m1.z*c1.z + m1.w*d1.z;
                        acc1[7] += m1.x*a1.w + m1.y*b1.w + m1.z*c1.w + m1.w*d1.w;
                    }
                } else {
                    const float* mp = rowb + (size_t)((v0 ? iw0 : iw1) + dw) * CIN2;
                    float* ac = v0 ? acc0 : acc1;
#pragma unroll 2
                    for (int ci = 0; ci < CIN2; ci += 4) {
                        const float* wb = wp2 + (size_t)ci * COUT;
                        float4 a0 = *(const float4*)(wb);
                        float4 a1 = *(const float4*)(wb + 4);
                        float4 b0 = *(const float4*)(wb + COUT);
                        float4 b1 = *(const float4*)(wb + COUT + 4);
                        float4 c0 = *(const float4*)(wb + 2 * COUT);
                        float4 c1 = *(const float4*)(wb + 2 * COUT + 4);
                        float4 d0 = *(const float4*)(wb + 3 * COUT);
                        float4 d1 = *(const float4*)(wb + 3 * COUT + 4);
                        float4 m0 = *(const float4*)(mp + ci);
                        ac[0] += m0.x*a0.x + m0.y*b0.x + m0.z*c0.x + m0.w*d0.x;
                        ac[1] += m0.x*a0.y + m0.y*b0.y + m0.z*c0.y + m0.w*d0.y;
                        ac[2] += m0.x*a0.z + m0.y*b0.z + m0.z*c0.z + m0.w*d0.z;
                        ac[3] += m0.x*a0.w + m0.y*b0.w + m0.z*c0.w + m0.w*d0.w;
                        ac[4] += m0.x*a1.x + m0.y*b1.x + m0.z*c1.x + m0.w*d1.x;
                        ac[5] += m0.x*a1.y + m0.y*b1.y + m0.z*c1.y + m0.w*d1.y;
                        ac[6] += m0.x*a1.z + m0.y*b1.z + m0.z*c1.z + m0.w*d1.z;
                        ac[7] += m0.x*a1.w + m0.y*b1.w + m0.z*c1.w + m0.w*d1.w;
                    }
                }
            }
        }
    }
    size_t pix0 = (size_t)(b * H + h) * W + w0;
    size_t o = pix0 * COUT + cog;
    float4 r0, r1;
    r0.x = fmaxf(acc0[0], 0.f); r0.y = fmaxf(acc0[1], 0.f);
    r0.z = fmaxf(acc0[2], 0.f); r0.w = fmaxf(acc0[3], 0.f);
    r1.x = fmaxf(acc0[4], 0.f); r1.y = fmaxf(acc0[5], 0.f);
    r1.z = fmaxf(acc0[6], 0.f); r1.w = fmaxf(acc0[7], 0.f);
    *(float4*)(mu_out + o) = r0;
    *(float4*)(mu_out + o + 4) = r1;
    if (pex1) {
        size_t o1 = o + COUT;
        float4 q0, q1;
        q0.x = fmaxf(acc1[0], 0.f); q0.y = fmaxf(acc1[1], 0.f);
        q0.z = fmaxf(acc1[2], 0.f); q0.w = fmaxf(acc1[3], 0.f);
        q1.x = fmaxf(acc1[4], 0.f); q1.y = fmaxf(acc1[5], 0.f);
        q1.z = fmaxf(acc1[6], 0.f); q1.w = fmaxf(acc1[7], 0.f);
        *(float4*)(mu_out + o1) = q0;
        *(float4*)(mu_out + o1 + 4) = q1;
    }
}

// ---- s conv via bf16 MFMA, LDS-free. Each wave: 16 pixels x 64 cout.
// s stored as hi+lo bf16 pair -> 2 MFMAs per (chunk, n-tile).
// s_out = (mu_out>0) ? q9*softplus + sum s*w^2 : 0.
__global__ void __launch_bounds__(256)
smfma_kernel(const unsigned short* __restrict__ s1h, const unsigned short* __restrict__ s1l,
             const unsigned short* __restrict__ s2h, const unsigned short* __restrict__ s2l,
             const float* __restrict__ q9v,
             const unsigned short* __restrict__ wTsq,
             const float* __restrict__ spv_,
             const float* __restrict__ muG,
             unsigned short* __restrict__ outH, unsigned short* __restrict__ outL,
             float* __restrict__ outF,
             int B_, int H, int W, int Cin1, int Cin2,
             int H2, int W2, int dh, int dw, int Cout)
{
    const int lane = threadIdx.x & 63;
    const int wave = threadIdx.x >> 6;
    const int total = B_ * H * W;
    const int Cin = Cin1 + Cin2;
    const int pixBase = blockIdx.x * 64 + wave * 16;
    const int coBase = blockIdx.y * 64;
    const int row = lane & 15;
    const int quad = lane >> 4;

    int P = pixBase + row;
    bool pv = P < total;
    int Pc = pv ? P : 0;
    int pb = Pc / (H * W);
    int r0i = Pc - pb * (H * W);
    int ph = r0i / W;
    int pw = r0i - ph * W;

    floatx4 acc[4];
#pragma unroll
    for (int i = 0; i < 4; i++) acc[i] = (floatx4){0.f, 0.f, 0.f, 0.f};
    const short8 zero8 = {0, 0, 0, 0, 0, 0, 0, 0};

    for (int tap = 0; tap < 9; tap++) {
        int kh = tap / 3, kw = tap - kh * 3;
        int ih = ph + kh - 1, iw = pw + kw - 1;
        bool tv = pv && ((unsigned)ih < (unsigned)H) && ((unsigned)iw < (unsigned)W);
        // source 1
        {
            size_t ab = ((size_t)(pb * H + ih) * W + iw) * (size_t)Cin1 + quad * 8;
            const unsigned short* __restrict__ wrow =
                wTsq + (size_t)(tap * Cout + coBase) * Cin + quad * 8;
            for (int kb = 0; kb < Cin1; kb += 32) {
                short8 ah = zero8, al = zero8;
                if (tv) {
                    ah = *(const short8*)(s1h + ab + kb);
                    al = *(const short8*)(s1l + ab + kb);
                }
#pragma unroll
                for (int nt = 0; nt < 4; nt++) {
                    short8 bf = *(const short8*)(wrow + (size_t)(nt * 16 + row) * Cin + kb);
                    acc[nt] = __builtin_amdgcn_mfma_f32_16x16x32_bf16(ah, bf, acc[nt], 0, 0, 0);
                    acc[nt] = __builtin_amdgcn_mfma_f32_16x16x32_bf16(al, bf, acc[nt], 0, 0, 0);
                }
            }
        }
        // source 2 (fused skip concat)
        if (Cin2 > 0) {
            size_t ab = ((size_t)(pb * H2 + ih + dh) * W2 + (iw + dw)) * (size_t)Cin2 + quad * 8;
            const unsigned short* __restrict__ wrow =
                wTsq + (size_t)(tap * Cout + coBase) * Cin + Cin1 + quad * 8;
            for (int kb = 0; kb < Cin2; kb += 32) {
                short8 ah = zero8, al = zero8;
                if (tv) {
                    ah = *(const short8*)(s2h + ab + kb);
                    al = *(const short8*)(s2l + ab + kb);
                }
#pragma unroll
                for (int nt = 0; nt < 4; nt++) {
                    short8 bf = *(const short8*)(wrow + (size_t)(nt * 16 + row) * Cin + kb);
                    acc[nt] = __builtin_amdgcn_mfma_f32_16x16x32_bf16(ah, bf, acc[nt], 0, 0, 0);
                    acc[nt] = __builtin_amdgcn_mfma_f32_16x16x32_bf16(al, bf, acc[nt], 0, 0, 0);
                }
            }
        }
    }

    // epilogue: D layout col(lane&15)=co, row(quad*4+r)=pixel
#pragma unroll
    for (int nt = 0; nt < 4; nt++) {
        int co = coBase + nt * 16 + row;
        float spv = spv_[co];
        floatx4 a = acc[nt];
#pragma unroll
        for (int r = 0; r < 4; r++) {
            int P2 = pixBase + quad * 4 + r;
            if (P2 < total) {
                size_t o = (size_t)P2 * Cout + co;
                float g = muG[o];
                float s = (g > 0.f) ? (q9v[P2] * spv + a[r]) : 0.f;
                if (outF) outF[o] = s;
                if (outH) {
                    unsigned short hh = f2bf(s);
                    outH[o] = hh;
                    outL[o] = f2bf(s - bfval(hh));
                }
            }
        }
    }
}

// ---- first layer (Cin=3): mu fp32 + s hi/lo
__global__ void conv_input_relu_kernel(const float* __restrict__ x,
                                       const float* __restrict__ w_mu,
                                       const float* __restrict__ w_sig,
                                       float* __restrict__ mu_out,
                                       unsigned short* __restrict__ s_hi,
                                       unsigned short* __restrict__ s_lo,
                                       int B_, int H, int W, int Cin, int Cout)
{
    int co = threadIdx.x;
    int pix = blockIdx.x * blockDim.y + threadIdx.y;
    int total = B_ * H * W;
    if (pix >= total) return;
    int b = pix / (H * W);
    int rem = pix % (H * W);
    int h = rem / W, w = rem % W;

    float mu = 0.f, q = 0.f;
    for (int kh = 0; kh < 3; kh++) {
        int ih = h + kh - 1;
        if (ih < 0 || ih >= H) continue;
        for (int kw = 0; kw < 3; kw++) {
            int iw = w + kw - 1;
            if (iw < 0 || iw >= W) continue;
            const float* xp = x + ((size_t)(b * H + ih) * W + iw) * Cin;
            const float* wp = w_mu + (size_t)((kh * 3 + kw) * Cin) * Cout + co;
            for (int ci = 0; ci < Cin; ci++) {
                float xv = xp[ci];
                mu += xv * wp[(size_t)ci * Cout];
                q += xv * xv;
            }
        }
    }
    float s = q * softplus_f(w_sig[co]);
    if (!(mu > 0.f)) { mu = 0.f; s = 0.f; }
    size_t oidx = (size_t)pix * Cout + co;
    mu_out[oidx] = mu;
    unsigned short hh = f2bf(s);
    s_hi[oidx] = hh;
    s_lo[oidx] = f2bf(s - bfval(hh));
}

// ---- unpool+conv (fp32 vector, in-register w^2, tq precomputed):
// mu out fp32 (relu'd), s out hi/lo bf16
__global__ void __launch_bounds__(256)
conv_unpool_fused(const float* __restrict__ mu_in,
                  const float* __restrict__ s_in,
                  const float* __restrict__ tq,
                  const float* __restrict__ w_mu,
                  const float* __restrict__ w_sig,
                  float* __restrict__ mu_out,
                  unsigned short* __restrict__ s_hi,
                  unsigned short* __restrict__ s_lo,
                  int B_, int Hin, int Win, int Cin,
                  int Hout, int Wout, int Cout)
{
    int cog = threadIdx.x * 4;
    int pix = blockIdx.x * blockDim.y + threadIdx.y;
    int total = B_ * Hout * Wout;
    if (pix >= total) return;
    int b = pix / (Hout * Wout);
    int rem = pix - b * (Hout * Wout);
    int ho = rem / Wout, wo = rem - (rem / Wout) * Wout;

    int khs[2], ihs[2], nkh;
    if (ho & 1) { nkh = 2; khs[0] = 0; ihs[0] = (ho - 1) >> 1; khs[1] = 2; ihs[1] = (ho + 1) >> 1; }
    else        { nkh = 1; khs[0] = 1; ihs[0] = ho >> 1; }
    int kws[2], iws[2], nkw;
    if (wo & 1) { nkw = 2; kws[0] = 0; iws[0] = (wo - 1) >> 1; kws[1] = 2; iws[1] = (wo + 1) >> 1; }
    else        { nkw = 1; kws[0] = 1; iws[0] = wo >> 1; }

    float4 amu = make_float4(0.f, 0.f, 0.f, 0.f);
    float4 asa = make_float4(0.f, 0.f, 0.f, 0.f);
    float q = 0.f;

    for (int a = 0; a < nkh; a++) {
        for (int c = 0; c < nkw; c++) {
            q += tq[(size_t)(b * Hin + ihs[a]) * Win + iws[c]];
            size_t base = ((size_t)(b * Hin + ihs[a]) * Win + iws[c]) * Cin;
            const float* mp = mu_in + base;
            const float* sp = s_in + base;
            const float* wp = w_mu + (size_t)((khs[a] * 3 + kws[c]) * Cin) * Cout + cog;
            for (int ci = 0; ci < Cin; ci += 4) {
                float4 m4 = *(const float4*)(mp + ci);
                float4 s4 = *(const float4*)(sp + ci);
                const float* wb = wp + (size_t)ci * Cout;
                float4 w0 = *(const float4*)(wb);
                float4 w1 = *(const float4*)(wb + Cout);
                float4 w2 = *(const float4*)(wb + 2 * Cout);
                float4 w3 = *(const float4*)(wb + 3 * Cout);
                amu.x += m4.x*w0.x + m4.y*w1.x + m4.z*w2.x + m4.w*w3.x;
                amu.y += m4.x*w0.y + m4.y*w1.y + m4.z*w2.y + m4.w*w3.y;
                amu.z += m4.x*w0.z + m4.y*w1.z + m4.z*w2.z + m4.w*w3.z;
                amu.w += m4.x*w0.w + m4.y*w1.w + m4.z*w2.w + m4.w*w3.w;
                asa.x += s4.x*(w0.x*w0.x) + s4.y*(w1.x*w1.x) + s4.z*(w2.x*w2.x) + s4.w*(w3.x*w3.x);
                asa.y += s4.x*(w0.y*w0.y) + s4.y*(w1.y*w1.y) + s4.z*(w2.y*w2.y) + s4.w*(w3.y*w3.y);
                asa.z += s4.x*(w0.z*w0.z) + s4.y*(w1.z*w1.z) + s4.z*(w2.z*w2.z) + s4.w*(w3.z*w3.z);
                asa.w += s4.x*(w0.w*w0.w) + s4.y*(w1.w*w1.w) + s4.z*(w2.w*w2.w) + s4.w*(w3.w*w3.w);
            }
        }
    }
    float4 sg = *(const float4*)(w_sig + cog);
    float4 so;
    so.x = q * softplus_f(sg.x) + asa.x;
    so.y = q * softplus_f(sg.y) + asa.y;
    so.z = q * softplus_f(sg.z) + asa.z;
    so.w = q * softplus_f(sg.w) + asa.w;
    if (!(amu.x > 0.f)) { amu.x = 0.f; so.x = 0.f; }
    if (!(amu.y > 0.f)) { amu.y = 0.f; so.y = 0.f; }
    if (!(amu.z > 0.f)) { amu.z = 0.f; so.z = 0.f; }
    if (!(amu.w > 0.f)) { amu.w = 0.f; so.w = 0.f; }
    size_t oidx = (size_t)pix * Cout + cog;
    *(float4*)(mu_out + oidx) = amu;
    unsigned short h0 = f2bf(so.x), h1 = f2bf(so.y), h2 = f2bf(so.z), h3 = f2bf(so.w);
    s_hi[oidx] = h0; s_hi[oidx + 1] = h1; s_hi[oidx + 2] = h2; s_hi[oidx + 3] = h3;
    s_lo[oidx]     = f2bf(so.x - bfval(h0));
    s_lo[oidx + 1] = f2bf(so.y - bfval(h1));
    s_lo[oidx + 2] = f2bf(so.z - bfval(h2));
    s_lo[oidx + 3] = f2bf(so.w - bfval(h3));
}

// ---- pool: mu fp32, s hi/lo gather at argmax
__global__ void pool_kernel(const float* __restrict__ mu_in,
                            const unsigned short* __restrict__ s_h,
                            const unsigned short* __restrict__ s_l,
                            float* __restrict__ mu_out,
                            unsigned short* __restrict__ so_h,
                            unsigned short* __restrict__ so_l,
                            int B_, int H, int W, int C)
{
    int Ho = H / 2, Wo = W / 2;
    size_t total = (size_t)B_ * Ho * Wo * C;
    size_t idx = (size_t)blockIdx.x * blockDim.x + threadIdx.x;
    if (idx >= total) return;
    int c = idx % C;
    size_t t = idx / C;
    int w = t % Wo; t /= Wo;
    int h = t % Ho;
    int b = t / Ho;
    size_t i0 = ((size_t)(b * H + 2 * h) * W + 2 * w) * C + c;
    size_t rowStride = (size_t)W * C;
    float m00 = mu_in[i0], m01 = mu_in[i0 + C];
    float m10 = mu_in[i0 + rowStride], m11 = mu_in[i0 + rowStride + C];
    int best = 0; float bm = m00;
    if (m01 > bm) { bm = m01; best = 1; }
    if (m10 > bm) { bm = m10; best = 2; }
    if (m11 > bm) { bm = m11; best = 3; }
    size_t off = (size_t)(best >> 1) * rowStride + (size_t)(best & 1) * C;
    mu_out[idx] = bm;
    so_h[idx] = s_h[i0 + off];
    so_l[idx] = s_l[i0 + off];
}

// ---- final 1x1 conv_inter + C=2 softmax density prop (fp32 in)
__global__ void final_kernel(const float* __restrict__ mu_in,
                             const float* __restrict__ s_in,
                             const float* __restrict__ w_mu,
                             const float* __restrict__ w_sig,
                             float* __restrict__ out,
                             int B_, int H, int W, int Cin)
{
    int pix = blockIdx.x * blockDim.x + threadIdx.x;
    int total = B_ * H * W;
    if (pix >= total) return;
    const float* mp = mu_in + (size_t)pix * Cin;
    const float* sp = s_in + (size_t)pix * Cin;
    float mu0 = 0.f, mu1 = 0.f, s0a = 0.f, s1a = 0.f, q = 0.f;
    for (int ci = 0; ci < Cin; ci += 4) {
        float4 m = *(const float4*)(mp + ci);
        float4 s = *(const float4*)(sp + ci);
        float4 wa = *(const float4*)(w_mu + ci * 2);
        float4 wb = *(const float4*)(w_mu + ci * 2 + 4);
        mu0 += m.x * wa.x + m.y * wa.z + m.z * wb.x + m.w * wb.z;
        mu1 += m.x * wa.y + m.y * wa.w + m.z * wb.y + m.w * wb.w;
        s0a += s.x * (wa.x * wa.x) + s.y * (wa.z * wa.z) + s.z * (wb.x * wb.x) + s.w * (wb.z * wb.z);
        s1a += s.x * (wa.y * wa.y) + s.y * (wa.w * wa.w) + s.z * (wb.y * wb.y) + s.w * (wb.w * wb.w);
        q += m.x * m.x + s.x + m.y * m.y + s.y + m.z * m.z + s.z + m.w * m.w + s.w;
    }
    float s0 = q * softplus_f(w_sig[0]) + s0a;
    float s1 = q * softplus_f(w_sig[1]) + s1a;
    float mx = fmaxf(mu0, mu1);
    float e0 = expf(mu0 - mx), e1 = expf(mu1 - mx);
    float inv = 1.f / (e0 + e1);
    float p0 = e0 * inv, p1 = e1 * inv;
    float g00 = p0 - p0 * p0, g01 = -p0 * p1;
    float g10 = -p1 * p0,     g11 = p1 - p1 * p1;
    float so0 = g00 * g00 * s0 + g01 * g01 * s1;
    float so1 = g10 * g10 * s0 + g11 * g11 * s1;
    out[(size_t)pix * 2]     = p0;
    out[(size_t)pix * 2 + 1] = p1;
    size_t off = (size_t)total * 2;
    out[off + (size_t)pix * 2]     = so0;
    out[off + (size_t)pix * 2 + 1] = so1;
}

// ---------------------------------------------------------------------------

extern "C" void kernel_launch(void* const* d_in, const int* in_sizes, int n_in,
                              void* d_out, int out_size, void* d_ws, size_t ws_size,
                              hipStream_t stream)
{
    const float* x = (const float*)d_in[0];
    enum { E1A, E1B, E2A, E2B, BA, BB, D2U, D2A, D2B, D1U, D1A, D1B, FIN, NW };
    const float* wmu[NW];
    const float* wsig[NW];
    for (int i = 0; i < NW; i++) {
        wmu[i]  = (const float*)d_in[1 + 2 * i];
        wsig[i] = (const float*)d_in[2 + 2 * i];
    }

    const int B_ = 4;
    float* ws = (float*)d_ws;
    float* M0   = ws;                        // 4194304
    float* M1   = ws + 4194304;              // 4194304
    float* E1mu = ws + 8388608;              // 4194304
    float* E2mu = ws + 12582912;             // 2097152
    float* SF   = ws + 14680064;             // 4194304 (fp32 s where needed)
    float* tq   = ws + 18874368;             // 65536
    float* q9   = ws + 18939904;             // 65536
    float* spb  = ws + 19005440;             // 2048
    unsigned short* us = (unsigned short*)(ws + 19007488);
    unsigned short* bS0h  = us;              // 4194304 each
    unsigned short* bS0l  = us + 4194304;
    unsigned short* bS1h  = us + 8388608;
    unsigned short* bS1l  = us + 12582912;
    unsigned short* bE1sh = us + 16777216;
    unsigned short* bE1sl = us + 20971520;
    unsigned short* bE2sh = us + 25165824;   // 2097152 each
    unsigned short* bE2sl = us + 27262976;
    unsigned short* wTsq  = us + 29360128;   // 1695744

    // MFMA layer table
    const int mlay[9]  = {E1B, E2A, E2B, BA, BB, D2A, D2B, D1A, D1B};
    const int mcin[9]  = {64, 64, 128, 128, 256, 256, 128, 128, 64};
    const int mcout[9] = {64, 128, 128, 256, 256, 128, 128, 64, 64};
    size_t woff[NW]; int spoff[NW];
    {
        size_t wo = 0; int so = 0;
        for (int i = 0; i < 9; i++) {
            int l = mlay[i];
            woff[l] = wo; spoff[l] = so;
            int n = 9 * mcin[i] * mcout[i];
            wprep_kernel<<<dim3((n + 255) / 256), dim3(256), 0, stream>>>(
                wmu[l], wTsq + wo, mcin[i], mcout[i], n);
            sp_kernel<<<dim3(1), dim3(256), 0, stream>>>(wsig[l], spb + so, mcout[i]);
            wo += n; so += mcout[i];
        }
    }

    // templated muconv dispatch
    auto launch_mu = [&](const float* muIn, const float* skMu,
                         int ci1, int ci2, int h2, int w2, int dh, int dw,
                         int H, int W, int widx, int cout, float* muOut) {
        int Wp = (W + 1) / 2;
        int totalP = B_ * H * Wp;
        int tx = cout / 8, ty = 256 / tx;
        dim3 grd((totalP + ty - 1) / ty);
        dim3 blk(tx, ty);
        const float* wm = wmu[widx];
        if (ci1 == 64 && ci2 == 0 && cout == 64)
            muconv_t<64, 0, 64><<<grd, blk, 0, stream>>>(muIn, skMu, wm, muOut, B_, H, W, h2, w2, dh, dw);
        else if (ci1 == 64 && ci2 == 0 && cout == 128)
            muconv_t<64, 0, 128><<<grd, blk, 0, stream>>>(muIn, skMu, wm, muOut, B_, H, W, h2, w2, dh, dw);
        else if (ci1 == 128 && ci2 == 0 && cout == 128)
            muconv_t<128, 0, 128><<<grd, blk, 0, stream>>>(muIn, skMu, wm, muOut, B_, H, W, h2, w2, dh, dw);
        else if (ci1 == 128 && ci2 == 0 && cout == 256)
            muconv_t<128, 0, 256><<<grd, blk, 0, stream>>>(muIn, skMu, wm, muOut, B_, H, W, h2, w2, dh, dw);
        else if (ci1 == 256 && ci2 == 0 && cout == 256)
            muconv_t<256, 0, 256><<<grd, blk, 0, stream>>>(muIn, skMu, wm, muOut, B_, H, W, h2, w2, dh, dw);
        else if (ci1 == 128 && ci2 == 128 && cout == 128)
            muconv_t<128, 128, 128><<<grd, blk, 0, stream>>>(muIn, skMu, wm, muOut, B_, H, W, h2, w2, dh, dw);
        else if (ci1 == 64 && ci2 == 64 && cout == 64)
            muconv_t<64, 64, 64><<<grd, blk, 0, stream>>>(muIn, skMu, wm, muOut, B_, H, W, h2, w2, dh, dw);
    };

    // full hybrid layer: t/q9 + mu vector conv (templated) + s MFMA
    auto layer = [&](const float* muIn, const unsigned short* sInH, const unsigned short* sInL,
                     int ci1,
                     const float* skMu, const unsigned short* skSH, const unsigned short* skSL,
                     int ci2, int h2, int w2, int dh, int dw,
                     int H, int W, int widx, int cout,
                     float* muOut, unsigned short* oH, unsigned short* oL, float* oF) {
        int total = B_ * H * W;
        t_mixed_kernel<<<dim3((total + 255) / 256), dim3(256), 0, stream>>>(
            muIn, sInH, sInL, skMu, skSH, skSL, tq, B_, H, W, ci1, ci2, h2, w2, dh, dw);
        q9_kernel<<<dim3((total + 255) / 256), dim3(256), 0, stream>>>(tq, q9, B_, H, W);
        launch_mu(muIn, skMu, ci1, ci2, h2, w2, dh, dw, H, W, widx, cout, muOut);
        smfma_kernel<<<dim3((total + 63) / 64, cout / 64), dim3(256), 0, stream>>>(
            sInH, sInL, skSH, skSL, q9, wTsq + woff[widx], spb + spoff[widx], muOut,
            oH, oL, oF, B_, H, W, ci1, ci2, h2, w2, dh, dw, cout);
    };

    auto unpool = [&](const float* mi, const float* si,
                      int hi, int wi, int ci, int ho, int wo, int co, int widx,
                      float* muOut, unsigned short* sH, unsigned short* sL) {
        int nin = B_ * hi * wi;
        t_f32_kernel<<<dim3((nin + 255) / 256), dim3(256), 0, stream>>>(mi, si, tq, nin, ci);
        int totalPix = B_ * ho * wo;
        int tx = co / 4, ty = 256 / tx;
        conv_unpool_fused<<<dim3((totalPix + ty - 1) / ty), dim3(tx, ty), 0, stream>>>(
            mi, si, tq, wmu[widx], wsig[widx], muOut, sH, sL,
            B_, hi, wi, ci, ho, wo, co);
    };

    // ---- encoder level 1 ----
    {
        int totalPix = B_ * 128 * 128;
        conv_input_relu_kernel<<<dim3((totalPix + 3) / 4), dim3(64, 4), 0, stream>>>(
            x, wmu[E1A], wsig[E1A], M0, bS0h, bS0l, B_, 128, 128, 3, 64);
    }
    layer(M0, bS0h, bS0l, 64, nullptr, nullptr, nullptr, 0, 0, 0, 0, 0,
          128, 128, E1B, 64, E1mu, bE1sh, bE1sl, nullptr);
    {
        size_t total = (size_t)B_ * 64 * 64 * 64;
        pool_kernel<<<dim3((total + 255) / 256), dim3(256), 0, stream>>>(
            E1mu, bE1sh, bE1sl, M0, bS0h, bS0l, B_, 128, 128, 64);
    }
    // ---- encoder level 2 ----
    layer(M0, bS0h, bS0l, 64, nullptr, nullptr, nullptr, 0, 0, 0, 0, 0,
          64, 64, E2A, 128, M1, bS1h, bS1l, nullptr);
    layer(M1, bS1h, bS1l, 128, nullptr, nullptr, nullptr, 0, 0, 0, 0, 0,
          64, 64, E2B, 128, E2mu, bE2sh, bE2sl, nullptr);
    {
        size_t total = (size_t)B_ * 32 * 32 * 128;
        pool_kernel<<<dim3((total + 255) / 256), dim3(256), 0, stream>>>(
            E2mu, bE2sh, bE2sl, M0, bS0h, bS0l, B_, 64, 64, 128);
    }
    // ---- bottleneck ----
    layer(M0, bS0h, bS0l, 128, nullptr, nullptr, nullptr, 0, 0, 0, 0, 0,
          32, 32, BA, 256, M1, bS1h, bS1l, nullptr);
    layer(M1, bS1h, bS1l, 256, nullptr, nullptr, nullptr, 0, 0, 0, 0, 0,
          32, 32, BB, 256, M0, nullptr, nullptr, SF);
    // ---- decoder level 2 ----
    unpool(M0, SF, 32, 32, 256, 63, 63, 128, D2U, M1, bS1h, bS1l);
    layer(M1, bS1h, bS1l, 128, E2mu, bE2sh, bE2sl, 128, 64, 64, 0, 0,
          63, 63, D2A, 128, M0, bS0h, bS0l, nullptr);
    layer(M0, bS0h, bS0l, 128, nullptr, nullptr, nullptr, 0, 0, 0, 0, 0,
          63, 63, D2B, 128, M1, nullptr, nullptr, SF);
    // ---- decoder level 1 ----
    unpool(M1, SF, 63, 63, 128, 125, 125, 64, D1U, M0, bS0h, bS0l);
    layer(M0, bS0h, bS0l, 64, E1mu, bE1sh, bE1sl, 64, 128, 128, 1, 1,
          125, 125, D1A, 64, M1, bS1h, bS1l, nullptr);
    layer(M1, bS1h, bS1l, 64, nullptr, nullptr, nullptr, 0, 0, 0, 0, 0,
          125, 125, D1B, 64, M0, nullptr, nullptr, SF);
    // ---- final 1x1 + softmax prop ----
    {
        int totalPix = B_ * 125 * 125;
        final_kernel<<<dim3((totalPix + 63) / 64), dim3(64), 0, stream>>>(
            M0, SF, wmu[FIN], wsig[FIN], (float*)d_out, B_, 125, 125, 64);
    }
}

// Round 9
// 2507.304 us; speedup vs baseline: 1.7015x; 1.7015x over previous
//
#include <hip/hip_runtime.h>
#include <math.h>

// ---------------------------------------------------------------------------
// Variance-propagating UNet (density prop), NHWC.
// Round 9: FULL-MFMA fused layer. mu stored as bf16 hi+lo pair; the mu-conv
// runs on matrix cores via 3-term split product (aH*wH + aL*wH + aH*wL,
// ~2^-18 rel err -> gates safe; round-5's single-bf16 at 2^-9 failed).
// s-conv stays the proven 2-MFMA hi/lo scheme. One kernel does both + relu
// gate from the exact fp32 accumulator. Vector mu-conv deleted (it was
// parallelism-starved: 1 wave/SIMD at 32x32 layers, VALUBusy 8.6%).
// ---------------------------------------------------------------------------

typedef __attribute__((ext_vector_type(8))) short short8;
typedef __attribute__((ext_vector_type(4))) float floatx4;

__device__ __forceinline__ float softplus_f(float x) { return log1pf(expf(x)); }

__device__ __forceinline__ unsigned short f2bf(float x) {
    unsigned int u = __float_as_uint(x);
    u = (u + 0x7FFF + ((u >> 16) & 1)) >> 16;
    return (unsigned short)u;
}
__device__ __forceinline__ float bfval(unsigned short h) {
    return __uint_as_float((unsigned int)h << 16);
}
__device__ __forceinline__ float bf2f_lo(unsigned int u) {
    return __uint_as_float(u << 16);
}
__device__ __forceinline__ float bf2f_hi(unsigned int u) {
    return __uint_as_float(u & 0xFFFF0000u);
}

// ---- weight prep: transposed [tap][co][ci]; w hi, w lo, w^2 (bf16)
__global__ void wprep3_kernel(const float* __restrict__ w,
                              unsigned short* __restrict__ wTh,
                              unsigned short* __restrict__ wTl,
                              unsigned short* __restrict__ wTsq,
                              int Cin, int Cout, int n)
{
    int idx = blockIdx.x * blockDim.x + threadIdx.x;
    if (idx >= n) return;
    int per = Cin * Cout;
    int tap = idx / per;
    int rem = idx - tap * per;
    int co = rem / Cin;
    int ci = rem - co * Cin;
    float v = w[(size_t)(tap * Cin + ci) * Cout + co];
    unsigned short hh = f2bf(v);
    wTh[idx] = hh;
    wTl[idx] = f2bf(v - bfval(hh));
    wTsq[idx] = f2bf(v * v);
}

__global__ void sp_kernel(const float* __restrict__ wsig,
                          float* __restrict__ sp, int n)
{
    int i = blockIdx.x * blockDim.x + threadIdx.x;
    if (i < n) sp[i] = softplus_f(wsig[i]);
}

// ---- t from hi/lo mu + hi/lo s (optional 2nd source at crop offset)
__global__ void t_hl_kernel(const unsigned short* __restrict__ m1h,
                            const unsigned short* __restrict__ m1l,
                            const unsigned short* __restrict__ s1h,
                            const unsigned short* __restrict__ s1l,
                            const unsigned short* __restrict__ m2h,
                            const unsigned short* __restrict__ m2l,
                            const unsigned short* __restrict__ s2h,
                            const unsigned short* __restrict__ s2l,
                            float* __restrict__ t_out,
                            int B_, int Hin, int Win, int Cin1, int Cin2,
                            int H2, int W2, int dh, int dw)
{
    int pix = blockIdx.x * blockDim.x + threadIdx.x;
    int total = B_ * Hin * Win;
    if (pix >= total) return;
    float acc = 0.f;
    {
        const unsigned short* mh = m1h + (size_t)pix * Cin1;
        const unsigned short* ml = m1l + (size_t)pix * Cin1;
        const unsigned short* sh = s1h + (size_t)pix * Cin1;
        const unsigned short* sl = s1l + (size_t)pix * Cin1;
        for (int ci = 0; ci < Cin1; ci += 8) {
            uint4 vmh = *(const uint4*)(mh + ci);
            uint4 vml = *(const uint4*)(ml + ci);
            uint4 vsh = *(const uint4*)(sh + ci);
            uint4 vsl = *(const uint4*)(sl + ci);
            float m0 = bf2f_lo(vmh.x) + bf2f_lo(vml.x), m1 = bf2f_hi(vmh.x) + bf2f_hi(vml.x);
            float m2 = bf2f_lo(vmh.y) + bf2f_lo(vml.y), m3 = bf2f_hi(vmh.y) + bf2f_hi(vml.y);
            float m4 = bf2f_lo(vmh.z) + bf2f_lo(vml.z), m5 = bf2f_hi(vmh.z) + bf2f_hi(vml.z);
            float m6 = bf2f_lo(vmh.w) + bf2f_lo(vml.w), m7 = bf2f_hi(vmh.w) + bf2f_hi(vml.w);
            acc += m0*m0 + m1*m1 + m2*m2 + m3*m3 + m4*m4 + m5*m5 + m6*m6 + m7*m7;
            acc += bf2f_lo(vsh.x) + bf2f_hi(vsh.x) + bf2f_lo(vsh.y) + bf2f_hi(vsh.y)
                 + bf2f_lo(vsh.z) + bf2f_hi(vsh.z) + bf2f_lo(vsh.w) + bf2f_hi(vsh.w);
            acc += bf2f_lo(vsl.x) + bf2f_hi(vsl.x) + bf2f_lo(vsl.y) + bf2f_hi(vsl.y)
                 + bf2f_lo(vsl.z) + bf2f_hi(vsl.z) + bf2f_lo(vsl.w) + bf2f_hi(vsl.w);
        }
    }
    if (Cin2 > 0) {
        int b = pix / (Hin * Win);
        int rem = pix - b * (Hin * Win);
        int h = rem / Win, w = rem - (rem / Win) * Win;
        size_t base = ((size_t)(b * H2 + h + dh) * W2 + (w + dw)) * Cin2;
        const unsigned short* mh = m2h + base;
        const unsigned short* ml = m2l + base;
        const unsigned short* sh = s2h + base;
        const unsigned short* sl = s2l + base;
        for (int ci = 0; ci < Cin2; ci += 8) {
            uint4 vmh = *(const uint4*)(mh + ci);
            uint4 vml = *(const uint4*)(ml + ci);
            uint4 vsh = *(const uint4*)(sh + ci);
            uint4 vsl = *(const uint4*)(sl + ci);
            float m0 = bf2f_lo(vmh.x) + bf2f_lo(vml.x), m1 = bf2f_hi(vmh.x) + bf2f_hi(vml.x);
            float m2 = bf2f_lo(vmh.y) + bf2f_lo(vml.y), m3 = bf2f_hi(vmh.y) + bf2f_hi(vml.y);
            float m4 = bf2f_lo(vmh.z) + bf2f_lo(vml.z), m5 = bf2f_hi(vmh.z) + bf2f_hi(vml.z);
            float m6 = bf2f_lo(vmh.w) + bf2f_lo(vml.w), m7 = bf2f_hi(vmh.w) + bf2f_hi(vml.w);
            acc += m0*m0 + m1*m1 + m2*m2 + m3*m3 + m4*m4 + m5*m5 + m6*m6 + m7*m7;
            acc += bf2f_lo(vsh.x) + bf2f_hi(vsh.x) + bf2f_lo(vsh.y) + bf2f_hi(vsh.y)
                 + bf2f_lo(vsh.z) + bf2f_hi(vsh.z) + bf2f_lo(vsh.w) + bf2f_hi(vsh.w);
            acc += bf2f_lo(vsl.x) + bf2f_hi(vsl.x) + bf2f_lo(vsl.y) + bf2f_hi(vsl.y)
                 + bf2f_lo(vsl.z) + bf2f_hi(vsl.z) + bf2f_lo(vsl.w) + bf2f_hi(vsl.w);
        }
    }
    t_out[pix] = acc;
}

// ---- t from fp32 mu + fp32 s (for unpool-conv inputs)
__global__ void t_f32_kernel(const float* __restrict__ mu1, const float* __restrict__ s1,
                             float* __restrict__ t_out, int total, int Cin)
{
    int pix = blockIdx.x * blockDim.x + threadIdx.x;
    if (pix >= total) return;
    const float* mp = mu1 + (size_t)pix * Cin;
    const float* sp = s1 + (size_t)pix * Cin;
    float acc = 0.f;
    for (int ci = 0; ci < Cin; ci += 4) {
        float4 m = *(const float4*)(mp + ci);
        float4 s = *(const float4*)(sp + ci);
        acc += m.x * m.x + s.x + m.y * m.y + s.y
             + m.z * m.z + s.z + m.w * m.w + s.w;
    }
    t_out[pix] = acc;
}

// ---- q9: sum t over valid 3x3 taps (pad=1)
__global__ void q9_kernel(const float* __restrict__ t_in,
                          float* __restrict__ q9, int B_, int H, int W)
{
    int pix = blockIdx.x * blockDim.x + threadIdx.x;
    int total = B_ * H * W;
    if (pix >= total) return;
    int b = pix / (H * W);
    int rem = pix - b * (H * W);
    int h = rem / W, w = rem - (rem / W) * W;
    float acc = 0.f;
    for (int kh = 0; kh < 3; kh++) {
        int ih = h + kh - 1;
        if ((unsigned)ih >= (unsigned)H) continue;
        for (int kw = 0; kw < 3; kw++) {
            int iw = w + kw - 1;
            if ((unsigned)iw >= (unsigned)W) continue;
            acc += t_in[(size_t)(b * H + ih) * W + iw];
        }
    }
    q9[pix] = acc;
}

// ---- FUSED MFMA layer: mu (3-MFMA split product) + s (2-MFMA hi/lo) + gate.
// Each wave: 16 pixels x 64 cout. A-frags loaded per-lane, LDS-free.
__global__ void __launch_bounds__(256)
fused_layer_kernel(const unsigned short* __restrict__ m1h, const unsigned short* __restrict__ m1l,
                   const unsigned short* __restrict__ s1h, const unsigned short* __restrict__ s1l,
                   const unsigned short* __restrict__ m2h, const unsigned short* __restrict__ m2l,
                   const unsigned short* __restrict__ s2h, const unsigned short* __restrict__ s2l,
                   const float* __restrict__ q9v,
                   const unsigned short* __restrict__ wTh, const unsigned short* __restrict__ wTl,
                   const unsigned short* __restrict__ wTsq,
                   const float* __restrict__ spv_,
                   float* __restrict__ oMf, float* __restrict__ oSf,
                   unsigned short* __restrict__ oMh, unsigned short* __restrict__ oMl,
                   unsigned short* __restrict__ oSh, unsigned short* __restrict__ oSl,
                   int B_, int H, int W, int Cin1, int Cin2,
                   int H2, int W2, int dh, int dw, int Cout)
{
    const int lane = threadIdx.x & 63;
    const int wave = threadIdx.x >> 6;
    const int total = B_ * H * W;
    const int Cin = Cin1 + Cin2;
    const int pixBase = blockIdx.x * 64 + wave * 16;
    const int coBase = blockIdx.y * 64;
    const int row = lane & 15;
    const int quad = lane >> 4;

    int P = pixBase + row;
    bool pv = P < total;
    int Pc = pv ? P : 0;
    int pb = Pc / (H * W);
    int r0i = Pc - pb * (H * W);
    int ph = r0i / W;
    int pw = r0i - ph * W;

    floatx4 accM[4], accS[4];
#pragma unroll
    for (int i = 0; i < 4; i++) {
        accM[i] = (floatx4){0.f, 0.f, 0.f, 0.f};
        accS[i] = (floatx4){0.f, 0.f, 0.f, 0.f};
    }
    const short8 zero8 = {0, 0, 0, 0, 0, 0, 0, 0};

    for (int tap = 0; tap < 9; tap++) {
        int kh = tap / 3, kw = tap - kh * 3;
        int ih = ph + kh - 1, iw = pw + kw - 1;
        bool tv = pv && ((unsigned)ih < (unsigned)H) && ((unsigned)iw < (unsigned)W);
        // source 1
        {
            size_t ab = ((size_t)(pb * H + ih) * W + iw) * (size_t)Cin1 + quad * 8;
            const size_t wbase = (size_t)(tap * Cout + coBase) * Cin + quad * 8;
            for (int kb = 0; kb < Cin1; kb += 32) {
                short8 aMh = zero8, aMl = zero8, aSh = zero8, aSl = zero8;
                if (tv) {
                    aMh = *(const short8*)(m1h + ab + kb);
                    aMl = *(const short8*)(m1l + ab + kb);
                    aSh = *(const short8*)(s1h + ab + kb);
                    aSl = *(const short8*)(s1l + ab + kb);
                }
#pragma unroll
                for (int nt = 0; nt < 4; nt++) {
                    size_t wo = wbase + (size_t)(nt * 16 + row) * Cin + kb;
                    short8 bh = *(const short8*)(wTh + wo);
                    short8 bl = *(const short8*)(wTl + wo);
                    short8 bq = *(const short8*)(wTsq + wo);
                    accM[nt] = __builtin_amdgcn_mfma_f32_16x16x32_bf16(aMh, bh, accM[nt], 0, 0, 0);
                    accM[nt] = __builtin_amdgcn_mfma_f32_16x16x32_bf16(aMl, bh, accM[nt], 0, 0, 0);
                    accM[nt] = __builtin_amdgcn_mfma_f32_16x16x32_bf16(aMh, bl, accM[nt], 0, 0, 0);
                    accS[nt] = __builtin_amdgcn_mfma_f32_16x16x32_bf16(aSh, bq, accS[nt], 0, 0, 0);
                    accS[nt] = __builtin_amdgcn_mfma_f32_16x16x32_bf16(aSl, bq, accS[nt], 0, 0, 0);
                }
            }
        }
        // source 2 (fused skip concat)
        if (Cin2 > 0) {
            size_t ab = ((size_t)(pb * H2 + ih + dh) * W2 + (iw + dw)) * (size_t)Cin2 + quad * 8;
            const size_t wbase = (size_t)(tap * Cout + coBase) * Cin + Cin1 + quad * 8;
            for (int kb = 0; kb < Cin2; kb += 32) {
                short8 aMh = zero8, aMl = zero8, aSh = zero8, aSl = zero8;
                if (tv) {
                    aMh = *(const short8*)(m2h + ab + kb);
                    aMl = *(const short8*)(m2l + ab + kb);
                    aSh = *(const short8*)(s2h + ab + kb);
                    aSl = *(const short8*)(s2l + ab + kb);
                }
#pragma unroll
                for (int nt = 0; nt < 4; nt++) {
                    size_t wo = wbase + (size_t)(nt * 16 + row) * Cin + kb;
                    short8 bh = *(const short8*)(wTh + wo);
                    short8 bl = *(const short8*)(wTl + wo);
                    short8 bq = *(const short8*)(wTsq + wo);
                    accM[nt] = __builtin_amdgcn_mfma_f32_16x16x32_bf16(aMh, bh, accM[nt], 0, 0, 0);
                    accM[nt] = __builtin_amdgcn_mfma_f32_16x16x32_bf16(aMl, bh, accM[nt], 0, 0, 0);
                    accM[nt] = __builtin_amdgcn_mfma_f32_16x16x32_bf16(aMh, bl, accM[nt], 0, 0, 0);
                    accS[nt] = __builtin_amdgcn_mfma_f32_16x16x32_bf16(aSh, bq, accS[nt], 0, 0, 0);
                    accS[nt] = __builtin_amdgcn_mfma_f32_16x16x32_bf16(aSl, bq, accS[nt], 0, 0, 0);
                }
            }
        }
    }

    // epilogue: D layout col(lane&15)=co, row(quad*4+r)=pixel; relu gate from
    // the exact fp32 mu accumulator.
#pragma unroll
    for (int nt = 0; nt < 4; nt++) {
        int co = coBase + nt * 16 + row;
        float spv = spv_[co];
        floatx4 am = accM[nt];
        floatx4 as = accS[nt];
#pragma unroll
        for (int r = 0; r < 4; r++) {
            int P2 = pixBase + quad * 4 + r;
            if (P2 < total) {
                size_t o = (size_t)P2 * Cout + co;
                float mu = am[r];
                float s = q9v[P2] * spv + as[r];
                if (!(mu > 0.f)) { mu = 0.f; s = 0.f; }
                if (oMf) oMf[o] = mu;
                if (oSf) oSf[o] = s;
                if (oMh) {
                    unsigned short mh = f2bf(mu);
                    oMh[o] = mh;
                    oMl[o] = f2bf(mu - bfval(mh));
                    unsigned short sh = f2bf(s);
                    oSh[o] = sh;
                    oSl[o] = f2bf(s - bfval(sh));
                }
            }
        }
    }
}

// ---- first layer (Cin=3): hi/lo outputs
__global__ void conv_input_relu_kernel(const float* __restrict__ x,
                                       const float* __restrict__ w_mu,
                                       const float* __restrict__ w_sig,
                                       unsigned short* __restrict__ m_h,
                                       unsigned short* __restrict__ m_l,
                                       unsigned short* __restrict__ s_h,
                                       unsigned short* __restrict__ s_l,
                                       int B_, int H, int W, int Cin, int Cout)
{
    int co = threadIdx.x;
    int pix = blockIdx.x * blockDim.y + threadIdx.y;
    int total = B_ * H * W;
    if (pix >= total) return;
    int b = pix / (H * W);
    int rem = pix % (H * W);
    int h = rem / W, w = rem % W;

    float mu = 0.f, q = 0.f;
    for (int kh = 0; kh < 3; kh++) {
        int ih = h + kh - 1;
        if (ih < 0 || ih >= H) continue;
        for (int kw = 0; kw < 3; kw++) {
            int iw = w + kw - 1;
            if (iw < 0 || iw >= W) continue;
            const float* xp = x + ((size_t)(b * H + ih) * W + iw) * Cin;
            const float* wp = w_mu + (size_t)((kh * 3 + kw) * Cin) * Cout + co;
            for (int ci = 0; ci < Cin; ci++) {
                float xv = xp[ci];
                mu += xv * wp[(size_t)ci * Cout];
                q += xv * xv;
            }
        }
    }
    float s = q * softplus_f(w_sig[co]);
    if (!(mu > 0.f)) { mu = 0.f; s = 0.f; }
    size_t oidx = (size_t)pix * Cout + co;
    unsigned short mh = f2bf(mu);
    m_h[oidx] = mh;
    m_l[oidx] = f2bf(mu - bfval(mh));
    unsigned short sh = f2bf(s);
    s_h[oidx] = sh;
    s_l[oidx] = f2bf(s - bfval(sh));
}

// ---- unpool+conv (fp32 vector): in fp32 mu/s; out hi/lo mu/s
__global__ void __launch_bounds__(256)
conv_unpool_fused(const float* __restrict__ mu_in,
                  const float* __restrict__ s_in,
                  const float* __restrict__ tq,
                  const float* __restrict__ w_mu,
                  const float* __restrict__ w_sig,
                  unsigned short* __restrict__ m_h,
                  unsigned short* __restrict__ m_l,
                  unsigned short* __restrict__ s_h,
                  unsigned short* __restrict__ s_l,
                  int B_, int Hin, int Win, int Cin,
                  int Hout, int Wout, int Cout)
{
    int cog = threadIdx.x * 4;
    int pix = blockIdx.x * blockDim.y + threadIdx.y;
    int total = B_ * Hout * Wout;
    if (pix >= total) return;
    int b = pix / (Hout * Wout);
    int rem = pix - b * (Hout * Wout);
    int ho = rem / Wout, wo = rem - (rem / Wout) * Wout;

    int khs[2], ihs[2], nkh;
    if (ho & 1) { nkh = 2; khs[0] = 0; ihs[0] = (ho - 1) >> 1; khs[1] = 2; ihs[1] = (ho + 1) >> 1; }
    else        { nkh = 1; khs[0] = 1; ihs[0] = ho >> 1; }
    int kws[2], iws[2], nkw;
    if (wo & 1) { nkw = 2; kws[0] = 0; iws[0] = (wo - 1) >> 1; kws[1] = 2; iws[1] = (wo + 1) >> 1; }
    else        { nkw = 1; kws[0] = 1; iws[0] = wo >> 1; }

    float4 amu = make_float4(0.f, 0.f, 0.f, 0.f);
    float4 asa = make_float4(0.f, 0.f, 0.f, 0.f);
    float q = 0.f;

    for (int a = 0; a < nkh; a++) {
        for (int c = 0; c < nkw; c++) {
            q += tq[(size_t)(b * Hin + ihs[a]) * Win + iws[c]];
            size_t base = ((size_t)(b * Hin + ihs[a]) * Win + iws[c]) * Cin;
            const float* mp = mu_in + base;
            const float* sp = s_in + base;
            const float* wp = w_mu + (size_t)((khs[a] * 3 + kws[c]) * Cin) * Cout + cog;
            for (int ci = 0; ci < Cin; ci += 4) {
                float4 m4 = *(const float4*)(mp + ci);
                float4 s4 = *(const float4*)(sp + ci);
                const float* wb = wp + (size_t)ci * Cout;
                float4 w0 = *(const float4*)(wb);
                float4 w1 = *(const float4*)(wb + Cout);
                float4 w2 = *(const float4*)(wb + 2 * Cout);
                float4 w3 = *(const float4*)(wb + 3 * Cout);
                amu.x += m4.x*w0.x + m4.y*w1.x + m4.z*w2.x + m4.w*w3.x;
                amu.y += m4.x*w0.y + m4.y*w1.y + m4.z*w2.y + m4.w*w3.y;
                amu.z += m4.x*w0.z + m4.y*w1.z + m4.z*w2.z + m4.w*w3.z;
                amu.w += m4.x*w0.w + m4.y*w1.w + m4.z*w2.w + m4.w*w3.w;
                asa.x += s4.x*(w0.x*w0.x) + s4.y*(w1.x*w1.x) + s4.z*(w2.x*w2.x) + s4.w*(w3.x*w3.x);
                asa.y += s4.x*(w0.y*w0.y) + s4.y*(w1.y*w1.y) + s4.z*(w2.y*w2.y) + s4.w*(w3.y*w3.y);
                asa.z += s4.x*(w0.z*w0.z) + s4.y*(w1.z*w1.z) + s4.z*(w2.z*w2.z) + s4.w*(w3.z*w3.z);
                asa.w += s4.x*(w0.w*w0.w) + s4.y*(w1.w*w1.w) + s4.z*(w2.w*w2.w) + s4.w*(w3.w*w3.w);
            }
        }
    }
    float4 sg = *(const float4*)(w_sig + cog);
    float4 so;
    so.x = q * softplus_f(sg.x) + asa.x;
    so.y = q * softplus_f(sg.y) + asa.y;
    so.z = q * softplus_f(sg.z) + asa.z;
    so.w = q * softplus_f(sg.w) + asa.w;
    if (!(amu.x > 0.f)) { amu.x = 0.f; so.x = 0.f; }
    if (!(amu.y > 0.f)) { amu.y = 0.f; so.y = 0.f; }
    if (!(amu.z > 0.f)) { amu.z = 0.f; so.z = 0.f; }
    if (!(amu.w > 0.f)) { amu.w = 0.f; so.w = 0.f; }
    size_t oidx = (size_t)pix * Cout + cog;
    float mus[4] = {amu.x, amu.y, amu.z, amu.w};
    float sos[4] = {so.x, so.y, so.z, so.w};
#pragma unroll
    for (int i = 0; i < 4; i++) {
        unsigned short mh = f2bf(mus[i]);
        m_h[oidx + i] = mh;
        m_l[oidx + i] = f2bf(mus[i] - bfval(mh));
        unsigned short sh = f2bf(sos[i]);
        s_h[oidx + i] = sh;
        s_l[oidx + i] = f2bf(sos[i] - bfval(sh));
    }
}

// ---- pool: fp32 mu for argmax; outputs hi/lo mu + gathered hi/lo s
__global__ void pool_kernel(const float* __restrict__ mu_in,
                            const unsigned short* __restrict__ s_h,
                            const unsigned short* __restrict__ s_l,
                            unsigned short* __restrict__ pm_h,
                            unsigned short* __restrict__ pm_l,
                            unsigned short* __restrict__ ps_h,
                            unsigned short* __restrict__ ps_l,
                            int B_, int H, int W, int C)
{
    int Ho = H / 2, Wo = W / 2;
    size_t total = (size_t)B_ * Ho * Wo * C;
    size_t idx = (size_t)blockIdx.x * blockDim.x + threadIdx.x;
    if (idx >= total) return;
    int c = idx % C;
    size_t t = idx / C;
    int w = t % Wo; t /= Wo;
    int h = t % Ho;
    int b = t / Ho;
    size_t i0 = ((size_t)(b * H + 2 * h) * W + 2 * w) * C + c;
    size_t rowStride = (size_t)W * C;
    float m00 = mu_in[i0], m01 = mu_in[i0 + C];
    float m10 = mu_in[i0 + rowStride], m11 = mu_in[i0 + rowStride + C];
    int best = 0; float bm = m00;
    if (m01 > bm) { bm = m01; best = 1; }
    if (m10 > bm) { bm = m10; best = 2; }
    if (m11 > bm) { bm = m11; best = 3; }
    size_t off = (size_t)(best >> 1) * rowStride + (size_t)(best & 1) * C;
    unsigned short mh = f2bf(bm);
    pm_h[idx] = mh;
    pm_l[idx] = f2bf(bm - bfval(mh));
    ps_h[idx] = s_h[i0 + off];
    ps_l[idx] = s_l[i0 + off];
}

// ---- final 1x1 conv_inter + C=2 softmax density prop (fp32 in)
__global__ void final_kernel(const float* __restrict__ mu_in,
                             const float* __restrict__ s_in,
                             const float* __restrict__ w_mu,
                             const float* __restrict__ w_sig,
                             float* __restrict__ out,
                             int B_, int H, int W, int Cin)
{
    int pix = blockIdx.x * blockDim.x + threadIdx.x;
    int total = B_ * H * W;
    if (pix >= total) return;
    const float* mp = mu_in + (size_t)pix * Cin;
    const float* sp = s_in + (size_t)pix * Cin;
    float mu0 = 0.f, mu1 = 0.f, s0a = 0.f, s1a = 0.f, q = 0.f;
    for (int ci = 0; ci < Cin; ci += 4) {
        float4 m = *(const float4*)(mp + ci);
        float4 s = *(const float4*)(sp + ci);
        float4 wa = *(const float4*)(w_mu + ci * 2);
        float4 wb = *(const float4*)(w_mu + ci * 2 + 4);
        mu0 += m.x * wa.x + m.y * wa.z + m.z * wb.x + m.w * wb.z;
        mu1 += m.x * wa.y + m.y * wa.w + m.z * wb.y + m.w * wb.w;
        s0a += s.x * (wa.x * wa.x) + s.y * (wa.z * wa.z) + s.z * (wb.x * wb.x) + s.w * (wb.z * wb.z);
        s1a += s.x * (wa.y * wa.y) + s.y * (wa.w * wa.w) + s.z * (wb.y * wb.y) + s.w * (wb.w * wb.w);
        q += m.x * m.x + s.x + m.y * m.y + s.y + m.z * m.z + s.z + m.w * m.w + s.w;
    }
    float s0 = q * softplus_f(w_sig[0]) + s0a;
    float s1 = q * softplus_f(w_sig[1]) + s1a;
    float mx = fmaxf(mu0, mu1);
    float e0 = expf(mu0 - mx), e1 = expf(mu1 - mx);
    float inv = 1.f / (e0 + e1);
    float p0 = e0 * inv, p1 = e1 * inv;
    float g00 = p0 - p0 * p0, g01 = -p0 * p1;
    float g10 = -p1 * p0,     g11 = p1 - p1 * p1;
    float so0 = g00 * g00 * s0 + g01 * g01 * s1;
    float so1 = g10 * g10 * s0 + g11 * g11 * s1;
    out[(size_t)pix * 2]     = p0;
    out[(size_t)pix * 2 + 1] = p1;
    size_t off = (size_t)total * 2;
    out[off + (size_t)pix * 2]     = so0;
    out[off + (size_t)pix * 2 + 1] = so1;
}

// ---------------------------------------------------------------------------

extern "C" void kernel_launch(void* const* d_in, const int* in_sizes, int n_in,
                              void* d_out, int out_size, void* d_ws, size_t ws_size,
                              hipStream_t stream)
{
    const float* x = (const float*)d_in[0];
    enum { E1A, E1B, E2A, E2B, BA, BB, D2U, D2A, D2B, D1U, D1A, D1B, FIN, NW };
    const float* wmu[NW];
    const float* wsig[NW];
    for (int i = 0; i < NW; i++) {
        wmu[i]  = (const float*)d_in[1 + 2 * i];
        wsig[i] = (const float*)d_in[2 + 2 * i];
    }

    const int B_ = 4;
    float* ws = (float*)d_ws;
    float* M0  = ws;                         // 4194304 fp32 mu scratch
    float* SF  = ws + 4194304;               // 4194304 fp32 s scratch
    float* tq  = ws + 8388608;               // 65536
    float* q9  = ws + 8454144;               // 65536
    float* spb = ws + 8519680;               // 2048
    unsigned short* us = (unsigned short*)(ws + 8521728);
    const size_t NB = 4194304;
    unsigned short* aMh = us;                // A set
    unsigned short* aMl = us + NB;
    unsigned short* aSh = us + 2 * NB;
    unsigned short* aSl = us + 3 * NB;
    unsigned short* bMh = us + 4 * NB;       // B set
    unsigned short* bMl = us + 5 * NB;
    unsigned short* bSh = us + 6 * NB;
    unsigned short* bSl = us + 7 * NB;
    unsigned short* e1Mh = us + 8 * NB;      // E1 skip
    unsigned short* e1Ml = us + 9 * NB;
    unsigned short* e1Sh = us + 10 * NB;
    unsigned short* e1Sl = us + 11 * NB;
    unsigned short* e2Mh = us + 12 * NB;     // E2 skip (2097152 each)
    unsigned short* e2Ml = e2Mh + 2097152;
    unsigned short* e2Sh = e2Ml + 2097152;
    unsigned short* e2Sl = e2Sh + 2097152;
    unsigned short* wTh  = e2Sl + 2097152;   // 1695744 each
    unsigned short* wTl  = wTh + 1695744;
    unsigned short* wTsq = wTl + 1695744;

    // fused-layer table
    const int mlay[9]  = {E1B, E2A, E2B, BA, BB, D2A, D2B, D1A, D1B};
    const int mcin[9]  = {64, 64, 128, 128, 256, 256, 128, 128, 64};
    const int mcout[9] = {64, 128, 128, 256, 256, 128, 128, 64, 64};
    size_t woff[NW]; int spoff[NW];
    {
        size_t wo = 0; int so = 0;
        for (int i = 0; i < 9; i++) {
            int l = mlay[i];
            woff[l] = wo; spoff[l] = so;
            int n = 9 * mcin[i] * mcout[i];
            wprep3_kernel<<<dim3((n + 255) / 256), dim3(256), 0, stream>>>(
                wmu[l], wTh + wo, wTl + wo, wTsq + wo, mcin[i], mcout[i], n);
            sp_kernel<<<dim3(1), dim3(256), 0, stream>>>(wsig[l], spb + so, mcout[i]);
            wo += n; so += mcout[i];
        }
    }

    // fused MFMA layer: t_hl + q9 + fused conv
    auto flayer = [&](const unsigned short* i_mh, const unsigned short* i_ml,
                      const unsigned short* i_sh, const unsigned short* i_sl, int ci1,
                      const unsigned short* k_mh, const unsigned short* k_ml,
                      const unsigned short* k_sh, const unsigned short* k_sl,
                      int ci2, int h2, int w2, int dh, int dw,
                      int H, int W, int widx, int cout,
                      float* oMf, float* oSf,
                      unsigned short* oMh, unsigned short* oMl,
                      unsigned short* oSh, unsigned short* oSl) {
        int total = B_ * H * W;
        t_hl_kernel<<<dim3((total + 255) / 256), dim3(256), 0, stream>>>(
            i_mh, i_ml, i_sh, i_sl, k_mh, k_ml, k_sh, k_sl, tq,
            B_, H, W, ci1, ci2, h2, w2, dh, dw);
        q9_kernel<<<dim3((total + 255) / 256), dim3(256), 0, stream>>>(tq, q9, B_, H, W);
        fused_layer_kernel<<<dim3((total + 63) / 64, cout / 64), dim3(256), 0, stream>>>(
            i_mh, i_ml, i_sh, i_sl, k_mh, k_ml, k_sh, k_sl, q9,
            wTh + woff[widx], wTl + woff[widx], wTsq + woff[widx], spb + spoff[widx],
            oMf, oSf, oMh, oMl, oSh, oSl,
            B_, H, W, ci1, ci2, h2, w2, dh, dw, cout);
    };

    auto unpool = [&](const float* mi, const float* si,
                      int hi, int wi, int ci, int ho, int wo, int co, int widx,
                      unsigned short* oMh, unsigned short* oMl,
                      unsigned short* oSh, unsigned short* oSl) {
        int nin = B_ * hi * wi;
        t_f32_kernel<<<dim3((nin + 255) / 256), dim3(256), 0, stream>>>(mi, si, tq, nin, ci);
        int totalPix = B_ * ho * wo;
        int tx = co / 4, ty = 256 / tx;
        conv_unpool_fused<<<dim3((totalPix + ty - 1) / ty), dim3(tx, ty), 0, stream>>>(
            mi, si, tq, wmu[widx], wsig[widx], oMh, oMl, oSh, oSl,
            B_, hi, wi, ci, ho, wo, co);
    };

    // ---- encoder level 1 ----
    {
        int totalPix = B_ * 128 * 128;
        conv_input_relu_kernel<<<dim3((totalPix + 3) / 4), dim3(64, 4), 0, stream>>>(
            x, wmu[E1A], wsig[E1A], aMh, aMl, aSh, aSl, B_, 128, 128, 3, 64);
    }
    // E1B: A -> E1 skip (hi/lo) + fp32 mu (M0) for pool argmax
    flayer(aMh, aMl, aSh, aSl, 64, nullptr, nullptr, nullptr, nullptr, 0, 0, 0, 0, 0,
           128, 128, E1B, 64, M0, nullptr, e1Mh, e1Ml, e1Sh, e1Sl);
    {
        size_t total = (size_t)B_ * 64 * 64 * 64;
        pool_kernel<<<dim3((total + 255) / 256), dim3(256), 0, stream>>>(
            M0, e1Sh, e1Sl, bMh, bMl, bSh, bSl, B_, 128, 128, 64);
    }
    // ---- encoder level 2 ----
    flayer(bMh, bMl, bSh, bSl, 64, nullptr, nullptr, nullptr, nullptr, 0, 0, 0, 0, 0,
           64, 64, E2A, 128, nullptr, nullptr, aMh, aMl, aSh, aSl);
    flayer(aMh, aMl, aSh, aSl, 128, nullptr, nullptr, nullptr, nullptr, 0, 0, 0, 0, 0,
           64, 64, E2B, 128, M0, nullptr, e2Mh, e2Ml, e2Sh, e2Sl);
    {
        size_t total = (size_t)B_ * 32 * 32 * 128;
        pool_kernel<<<dim3((total + 255) / 256), dim3(256), 0, stream>>>(
            M0, e2Sh, e2Sl, bMh, bMl, bSh, bSl, B_, 64, 64, 128);
    }
    // ---- bottleneck ----
    flayer(bMh, bMl, bSh, bSl, 128, nullptr, nullptr, nullptr, nullptr, 0, 0, 0, 0, 0,
           32, 32, BA, 256, nullptr, nullptr, aMh, aMl, aSh, aSl);
    flayer(aMh, aMl, aSh, aSl, 256, nullptr, nullptr, nullptr, nullptr, 0, 0, 0, 0, 0,
           32, 32, BB, 256, M0, SF, nullptr, nullptr, nullptr, nullptr);
    // ---- decoder level 2 ----
    unpool(M0, SF, 32, 32, 256, 63, 63, 128, D2U, bMh, bMl, bSh, bSl);
    flayer(bMh, bMl, bSh, bSl, 128, e2Mh, e2Ml, e2Sh, e2Sl, 128, 64, 64, 0, 0,
           63, 63, D2A, 128, nullptr, nullptr, aMh, aMl, aSh, aSl);
    flayer(aMh, aMl, aSh, aSl, 128, nullptr, nullptr, nullptr, nullptr, 0, 0, 0, 0, 0,
           63, 63, D2B, 128, M0, SF, nullptr, nullptr, nullptr, nullptr);
    // ---- decoder level 1 ----
    unpool(M0, SF, 63, 63, 128, 125, 125, 64, D1U, bMh, bMl, bSh, bSl);
    flayer(bMh, bMl, bSh, bSl, 64, e1Mh, e1Ml, e1Sh, e1Sl, 64, 128, 128, 1, 1,
           125, 125, D1A, 64, nullptr, nullptr, aMh, aMl, aSh, aSl);
    flayer(aMh, aMl, aSh, aSl, 64, nullptr, nullptr, nullptr, nullptr, 0, 0, 0, 0, 0,
           125, 125, D1B, 64, M0, SF, nullptr, nullptr, nullptr, nullptr);
    // ---- final 1x1 + softmax prop ----
    {
        int totalPix = B_ * 125 * 125;
        final_kernel<<<dim3((totalPix + 63) / 64), dim3(64), 0, stream>>>(
            M0, SF, wmu[FIN], wsig[FIN], (float*)d_out, B_, 125, 125, 64);
    }
}

// Round 11
// 2288.239 us; speedup vs baseline: 1.8644x; 1.0957x over previous
//
#include <hip/hip_runtime.h>
#include <math.h>

// ---------------------------------------------------------------------------
// Variance-propagating UNet (density prop), NHWC.
// Round 11: revert to round-9 numerics (9 dense convs on MFMA w/ split-
// product mu; unpool convs VECTOR with exact fp32 gates — round 10 proved
// MFMA gates on unpool layers blow the error budget: 6144 -> 14336).
// Unpool conv now processes 2 SAME-PARITY pixels (wo, wo+2) per thread:
// identical live-tap sets, weight loads + w^2 shared across the pair.
// ---------------------------------------------------------------------------

typedef __attribute__((ext_vector_type(8))) short short8;
typedef __attribute__((ext_vector_type(4))) float floatx4;

__device__ __forceinline__ float softplus_f(float x) { return log1pf(expf(x)); }

__device__ __forceinline__ unsigned short f2bf(float x) {
    unsigned int u = __float_as_uint(x);
    u = (u + 0x7FFF + ((u >> 16) & 1)) >> 16;
    return (unsigned short)u;
}
__device__ __forceinline__ float bfval(unsigned short h) {
    return __uint_as_float((unsigned int)h << 16);
}
__device__ __forceinline__ float bf2f_lo(unsigned int u) {
    return __uint_as_float(u << 16);
}
__device__ __forceinline__ float bf2f_hi(unsigned int u) {
    return __uint_as_float(u & 0xFFFF0000u);
}

// ---- weight prep: transposed [tap][co][ci]; w hi, w lo, w^2 (bf16)
__global__ void wprep3_kernel(const float* __restrict__ w,
                              unsigned short* __restrict__ wTh,
                              unsigned short* __restrict__ wTl,
                              unsigned short* __restrict__ wTsq,
                              int Cin, int Cout, int n)
{
    int idx = blockIdx.x * blockDim.x + threadIdx.x;
    if (idx >= n) return;
    int per = Cin * Cout;
    int tap = idx / per;
    int rem = idx - tap * per;
    int co = rem / Cin;
    int ci = rem - co * Cin;
    float v = w[(size_t)(tap * Cin + ci) * Cout + co];
    unsigned short hh = f2bf(v);
    wTh[idx] = hh;
    wTl[idx] = f2bf(v - bfval(hh));
    wTsq[idx] = f2bf(v * v);
}

__global__ void sp_kernel(const float* __restrict__ wsig,
                          float* __restrict__ sp, int n)
{
    int i = blockIdx.x * blockDim.x + threadIdx.x;
    if (i < n) sp[i] = softplus_f(wsig[i]);
}

// ---- t from hi/lo mu + hi/lo s (optional 2nd source at crop offset)
__global__ void t_hl_kernel(const unsigned short* __restrict__ m1h,
                            const unsigned short* __restrict__ m1l,
                            const unsigned short* __restrict__ s1h,
                            const unsigned short* __restrict__ s1l,
                            const unsigned short* __restrict__ m2h,
                            const unsigned short* __restrict__ m2l,
                            const unsigned short* __restrict__ s2h,
                            const unsigned short* __restrict__ s2l,
                            float* __restrict__ t_out,
                            int B_, int Hin, int Win, int Cin1, int Cin2,
                            int H2, int W2, int dh, int dw)
{
    int pix = blockIdx.x * blockDim.x + threadIdx.x;
    int total = B_ * Hin * Win;
    if (pix >= total) return;
    float acc = 0.f;
    {
        const unsigned short* mh = m1h + (size_t)pix * Cin1;
        const unsigned short* ml = m1l + (size_t)pix * Cin1;
        const unsigned short* sh = s1h + (size_t)pix * Cin1;
        const unsigned short* sl = s1l + (size_t)pix * Cin1;
        for (int ci = 0; ci < Cin1; ci += 8) {
            uint4 vmh = *(const uint4*)(mh + ci);
            uint4 vml = *(const uint4*)(ml + ci);
            uint4 vsh = *(const uint4*)(sh + ci);
            uint4 vsl = *(const uint4*)(sl + ci);
            float m0 = bf2f_lo(vmh.x) + bf2f_lo(vml.x), m1 = bf2f_hi(vmh.x) + bf2f_hi(vml.x);
            float m2 = bf2f_lo(vmh.y) + bf2f_lo(vml.y), m3 = bf2f_hi(vmh.y) + bf2f_hi(vml.y);
            float m4 = bf2f_lo(vmh.z) + bf2f_lo(vml.z), m5 = bf2f_hi(vmh.z) + bf2f_hi(vml.z);
            float m6 = bf2f_lo(vmh.w) + bf2f_lo(vml.w), m7 = bf2f_hi(vmh.w) + bf2f_hi(vml.w);
            acc += m0*m0 + m1*m1 + m2*m2 + m3*m3 + m4*m4 + m5*m5 + m6*m6 + m7*m7;
            acc += bf2f_lo(vsh.x) + bf2f_hi(vsh.x) + bf2f_lo(vsh.y) + bf2f_hi(vsh.y)
                 + bf2f_lo(vsh.z) + bf2f_hi(vsh.z) + bf2f_lo(vsh.w) + bf2f_hi(vsh.w);
            acc += bf2f_lo(vsl.x) + bf2f_hi(vsl.x) + bf2f_lo(vsl.y) + bf2f_hi(vsl.y)
                 + bf2f_lo(vsl.z) + bf2f_hi(vsl.z) + bf2f_lo(vsl.w) + bf2f_hi(vsl.w);
        }
    }
    if (Cin2 > 0) {
        int b = pix / (Hin * Win);
        int rem = pix - b * (Hin * Win);
        int h = rem / Win, w = rem - (rem / Win) * Win;
        size_t base = ((size_t)(b * H2 + h + dh) * W2 + (w + dw)) * Cin2;
        const unsigned short* mh = m2h + base;
        const unsigned short* ml = m2l + base;
        const unsigned short* sh = s2h + base;
        const unsigned short* sl = s2l + base;
        for (int ci = 0; ci < Cin2; ci += 8) {
            uint4 vmh = *(const uint4*)(mh + ci);
            uint4 vml = *(const uint4*)(ml + ci);
            uint4 vsh = *(const uint4*)(sh + ci);
            uint4 vsl = *(const uint4*)(sl + ci);
            float m0 = bf2f_lo(vmh.x) + bf2f_lo(vml.x), m1 = bf2f_hi(vmh.x) + bf2f_hi(vml.x);
            float m2 = bf2f_lo(vmh.y) + bf2f_lo(vml.y), m3 = bf2f_hi(vmh.y) + bf2f_hi(vml.y);
            float m4 = bf2f_lo(vmh.z) + bf2f_lo(vml.z), m5 = bf2f_hi(vmh.z) + bf2f_hi(vml.z);
            float m6 = bf2f_lo(vmh.w) + bf2f_lo(vml.w), m7 = bf2f_hi(vmh.w) + bf2f_hi(vml.w);
            acc += m0*m0 + m1*m1 + m2*m2 + m3*m3 + m4*m4 + m5*m5 + m6*m6 + m7*m7;
            acc += bf2f_lo(vsh.x) + bf2f_hi(vsh.x) + bf2f_lo(vsh.y) + bf2f_hi(vsh.y)
                 + bf2f_lo(vsh.z) + bf2f_hi(vsh.z) + bf2f_lo(vsh.w) + bf2f_hi(vsh.w);
            acc += bf2f_lo(vsl.x) + bf2f_hi(vsl.x) + bf2f_lo(vsl.y) + bf2f_hi(vsl.y)
                 + bf2f_lo(vsl.z) + bf2f_hi(vsl.z) + bf2f_lo(vsl.w) + bf2f_hi(vsl.w);
        }
    }
    t_out[pix] = acc;
}

// ---- t from fp32 mu + fp32 s (for unpool-conv inputs)
__global__ void t_f32_kernel(const float* __restrict__ mu1, const float* __restrict__ s1,
                             float* __restrict__ t_out, int total, int Cin)
{
    int pix = blockIdx.x * blockDim.x + threadIdx.x;
    if (pix >= total) return;
    const float* mp = mu1 + (size_t)pix * Cin;
    const float* sp = s1 + (size_t)pix * Cin;
    float acc = 0.f;
    for (int ci = 0; ci < Cin; ci += 4) {
        float4 m = *(const float4*)(mp + ci);
        float4 s = *(const float4*)(sp + ci);
        acc += m.x * m.x + s.x + m.y * m.y + s.y
             + m.z * m.z + s.z + m.w * m.w + s.w;
    }
    t_out[pix] = acc;
}

// ---- q9: sum t over valid 3x3 taps (pad=1)
__global__ void q9_kernel(const float* __restrict__ t_in,
                          float* __restrict__ q9, int B_, int H, int W)
{
    int pix = blockIdx.x * blockDim.x + threadIdx.x;
    int total = B_ * H * W;
    if (pix >= total) return;
    int b = pix / (H * W);
    int rem = pix - b * (H * W);
    int h = rem / W, w = rem - (rem / W) * W;
    float acc = 0.f;
    for (int kh = 0; kh < 3; kh++) {
        int ih = h + kh - 1;
        if ((unsigned)ih >= (unsigned)H) continue;
        for (int kw = 0; kw < 3; kw++) {
            int iw = w + kw - 1;
            if ((unsigned)iw >= (unsigned)W) continue;
            acc += t_in[(size_t)(b * H + ih) * W + iw];
        }
    }
    q9[pix] = acc;
}

// ---- FUSED MFMA layer (dense convs): mu (3-MFMA split) + s (2-MFMA hi/lo)
// + relu gate from the fp32 accumulator. Each wave: 16 pixels x 64 cout.
__global__ void __launch_bounds__(256)
fused_layer_kernel(const unsigned short* __restrict__ m1h, const unsigned short* __restrict__ m1l,
                   const unsigned short* __restrict__ s1h, const unsigned short* __restrict__ s1l,
                   const unsigned short* __restrict__ m2h, const unsigned short* __restrict__ m2l,
                   const unsigned short* __restrict__ s2h, const unsigned short* __restrict__ s2l,
                   const float* __restrict__ q9v,
                   const unsigned short* __restrict__ wTh, const unsigned short* __restrict__ wTl,
                   const unsigned short* __restrict__ wTsq,
                   const float* __restrict__ spv_,
                   float* __restrict__ oMf, float* __restrict__ oSf,
                   unsigned short* __restrict__ oMh, unsigned short* __restrict__ oMl,
                   unsigned short* __restrict__ oSh, unsigned short* __restrict__ oSl,
                   int B_, int H, int W, int Cin1, int Cin2,
                   int H2, int W2, int dh, int dw, int Cout)
{
    const int lane = threadIdx.x & 63;
    const int wave = threadIdx.x >> 6;
    const int total = B_ * H * W;
    const int Cin = Cin1 + Cin2;
    const int pixBase = blockIdx.x * 64 + wave * 16;
    const int coBase = blockIdx.y * 64;
    const int row = lane & 15;
    const int quad = lane >> 4;

    int P = pixBase + row;
    bool pv = P < total;
    int Pc = pv ? P : 0;
    int pb = Pc / (H * W);
    int r0i = Pc - pb * (H * W);
    int ph = r0i / W;
    int pw = r0i - ph * W;

    floatx4 accM[4], accS[4];
#pragma unroll
    for (int i = 0; i < 4; i++) {
        accM[i] = (floatx4){0.f, 0.f, 0.f, 0.f};
        accS[i] = (floatx4){0.f, 0.f, 0.f, 0.f};
    }
    const short8 zero8 = {0, 0, 0, 0, 0, 0, 0, 0};

    for (int tap = 0; tap < 9; tap++) {
        int kh = tap / 3, kw = tap - kh * 3;
        int ih = ph + kh - 1, iw = pw + kw - 1;
        bool tv = pv && ((unsigned)ih < (unsigned)H) && ((unsigned)iw < (unsigned)W);
        if (!tv) { ih = 0; iw = 0; }
        // source 1
        {
            size_t ab = ((size_t)(pb * H + ih) * W + iw) * (size_t)Cin1 + quad * 8;
            const size_t wbase = (size_t)(tap * Cout + coBase) * Cin + quad * 8;
            for (int kb = 0; kb < Cin1; kb += 32) {
                short8 aMh = zero8, aMl = zero8, aSh = zero8, aSl = zero8;
                if (tv) {
                    aMh = *(const short8*)(m1h + ab + kb);
                    aMl = *(const short8*)(m1l + ab + kb);
                    aSh = *(const short8*)(s1h + ab + kb);
                    aSl = *(const short8*)(s1l + ab + kb);
                }
#pragma unroll
                for (int nt = 0; nt < 4; nt++) {
                    size_t wo = wbase + (size_t)(nt * 16 + row) * Cin + kb;
                    short8 bh = *(const short8*)(wTh + wo);
                    short8 bl = *(const short8*)(wTl + wo);
                    short8 bq = *(const short8*)(wTsq + wo);
                    accM[nt] = __builtin_amdgcn_mfma_f32_16x16x32_bf16(aMh, bh, accM[nt], 0, 0, 0);
                    accM[nt] = __builtin_amdgcn_mfma_f32_16x16x32_bf16(aMl, bh, accM[nt], 0, 0, 0);
                    accM[nt] = __builtin_amdgcn_mfma_f32_16x16x32_bf16(aMh, bl, accM[nt], 0, 0, 0);
                    accS[nt] = __builtin_amdgcn_mfma_f32_16x16x32_bf16(aSh, bq, accS[nt], 0, 0, 0);
                    accS[nt] = __builtin_amdgcn_mfma_f32_16x16x32_bf16(aSl, bq, accS[nt], 0, 0, 0);
                }
            }
        }
        // source 2 (fused skip concat)
        if (Cin2 > 0) {
            size_t ab = ((size_t)(pb * H2 + ih + dh) * W2 + (iw + dw)) * (size_t)Cin2 + quad * 8;
            const size_t wbase = (size_t)(tap * Cout + coBase) * Cin + Cin1 + quad * 8;
            for (int kb = 0; kb < Cin2; kb += 32) {
                short8 aMh = zero8, aMl = zero8, aSh = zero8, aSl = zero8;
                if (tv) {
                    aMh = *(const short8*)(m2h + ab + kb);
                    aMl = *(const short8*)(m2l + ab + kb);
                    aSh = *(const short8*)(s2h + ab + kb);
                    aSl = *(const short8*)(s2l + ab + kb);
                }
#pragma unroll
                for (int nt = 0; nt < 4; nt++) {
                    size_t wo = wbase + (size_t)(nt * 16 + row) * Cin + kb;
                    short8 bh = *(const short8*)(wTh + wo);
                    short8 bl = *(const short8*)(wTl + wo);
                    short8 bq = *(const short8*)(wTsq + wo);
                    accM[nt] = __builtin_amdgcn_mfma_f32_16x16x32_bf16(aMh, bh, accM[nt], 0, 0, 0);
                    accM[nt] = __builtin_amdgcn_mfma_f32_16x16x32_bf16(aMl, bh, accM[nt], 0, 0, 0);
                    accM[nt] = __builtin_amdgcn_mfma_f32_16x16x32_bf16(aMh, bl, accM[nt], 0, 0, 0);
                    accS[nt] = __builtin_amdgcn_mfma_f32_16x16x32_bf16(aSh, bq, accS[nt], 0, 0, 0);
                    accS[nt] = __builtin_amdgcn_mfma_f32_16x16x32_bf16(aSl, bq, accS[nt], 0, 0, 0);
                }
            }
        }
    }

#pragma unroll
    for (int nt = 0; nt < 4; nt++) {
        int co = coBase + nt * 16 + row;
        float spv = spv_[co];
        floatx4 am = accM[nt];
        floatx4 as = accS[nt];
#pragma unroll
        for (int r = 0; r < 4; r++) {
            int P2 = pixBase + quad * 4 + r;
            if (P2 < total) {
                size_t o = (size_t)P2 * Cout + co;
                float mu = am[r];
                float s = q9v[P2] * spv + as[r];
                if (!(mu > 0.f)) { mu = 0.f; s = 0.f; }
                if (oMf) oMf[o] = mu;
                if (oSf) oSf[o] = s;
                if (oMh) {
                    unsigned short mh = f2bf(mu);
                    oMh[o] = mh;
                    oMl[o] = f2bf(mu - bfval(mh));
                    unsigned short sh = f2bf(s);
                    oSh[o] = sh;
                    oSl[o] = f2bf(s - bfval(sh));
                }
            }
        }
    }
}

// ---- first layer (Cin=3): hi/lo outputs
__global__ void conv_input_relu_kernel(const float* __restrict__ x,
                                       const float* __restrict__ w_mu,
                                       const float* __restrict__ w_sig,
                                       unsigned short* __restrict__ m_h,
                                       unsigned short* __restrict__ m_l,
                                       unsigned short* __restrict__ s_h,
                                       unsigned short* __restrict__ s_l,
                                       int B_, int H, int W, int Cin, int Cout)
{
    int co = threadIdx.x;
    int pix = blockIdx.x * blockDim.y + threadIdx.y;
    int total = B_ * H * W;
    if (pix >= total) return;
    int b = pix / (H * W);
    int rem = pix % (H * W);
    int h = rem / W, w = rem % W;

    float mu = 0.f, q = 0.f;
    for (int kh = 0; kh < 3; kh++) {
        int ih = h + kh - 1;
        if (ih < 0 || ih >= H) continue;
        for (int kw = 0; kw < 3; kw++) {
            int iw = w + kw - 1;
            if (iw < 0 || iw >= W) continue;
            const float* xp = x + ((size_t)(b * H + ih) * W + iw) * Cin;
            const float* wp = w_mu + (size_t)((kh * 3 + kw) * Cin) * Cout + co;
            for (int ci = 0; ci < Cin; ci++) {
                float xv = xp[ci];
                mu += xv * wp[(size_t)ci * Cout];
                q += xv * xv;
            }
        }
    }
    float s = q * softplus_f(w_sig[co]);
    if (!(mu > 0.f)) { mu = 0.f; s = 0.f; }
    size_t oidx = (size_t)pix * Cout + co;
    unsigned short mh = f2bf(mu);
    m_h[oidx] = mh;
    m_l[oidx] = f2bf(mu - bfval(mh));
    unsigned short sh = f2bf(s);
    s_h[oidx] = sh;
    s_l[oidx] = f2bf(s - bfval(sh));
}

// ---- unpool+conv (fp32 vector, exact gates): 2 SAME-PARITY pixels per
// thread (wo, wo+2) — identical live-tap sets, weight loads + w^2 shared.
// In: fp32 mu/s; out: hi/lo mu/s (bf16 pairs).
__global__ void __launch_bounds__(256)
conv_unpool_pair(const float* __restrict__ mu_in,
                 const float* __restrict__ s_in,
                 const float* __restrict__ tq,
                 const float* __restrict__ w_mu,
                 const float* __restrict__ w_sig,
                 unsigned short* __restrict__ m_h,
                 unsigned short* __restrict__ m_l,
                 unsigned short* __restrict__ s_h,
                 unsigned short* __restrict__ s_l,
                 int B_, int Hin, int Win, int Cin,
                 int Hout, int Wout, int Cout)
{
    int cog = threadIdx.x * 4;
    const int Wp = 2 * ((Wout + 3) >> 2);   // pair slots per row
    int pr = blockIdx.x * blockDim.y + threadIdx.y;
    int totalP = B_ * Hout * Wp;
    if (pr >= totalP) return;
    int b = pr / (Hout * Wp);
    int rem = pr - b * (Hout * Wp);
    int ho = rem / Wp;
    int k = rem - ho * Wp;
    int w0 = 4 * (k >> 1) + (k & 1);
    if (w0 >= Wout) return;
    int w1 = w0 + 2;
    const bool v1 = w1 < Wout;

    int khs[2], ihs[2], nkh;
    if (ho & 1) { nkh = 2; khs[0] = 0; ihs[0] = (ho - 1) >> 1; khs[1] = 2; ihs[1] = (ho + 1) >> 1; }
    else        { nkh = 1; khs[0] = 1; ihs[0] = ho >> 1; }
    int kws[2], iws[2], nkw;
    if (w0 & 1) { nkw = 2; kws[0] = 0; iws[0] = (w0 - 1) >> 1; kws[1] = 2; iws[1] = (w0 + 1) >> 1; }
    else        { nkw = 1; kws[0] = 1; iws[0] = w0 >> 1; }

    float4 amu0 = make_float4(0.f, 0.f, 0.f, 0.f);
    float4 asa0 = make_float4(0.f, 0.f, 0.f, 0.f);
    float4 amu1 = make_float4(0.f, 0.f, 0.f, 0.f);
    float4 asa1 = make_float4(0.f, 0.f, 0.f, 0.f);
    float q0 = 0.f, q1 = 0.f;

    for (int a = 0; a < nkh; a++) {
        for (int c = 0; c < nkw; c++) {
            size_t trow = (size_t)(b * Hin + ihs[a]) * Win + iws[c];
            q0 += tq[trow];
            if (v1) q1 += tq[trow + 1];
            size_t base0 = trow * Cin;
            const float* mp0 = mu_in + base0;
            const float* sp0 = s_in + base0;
            const float* mp1 = mp0 + Cin;
            const float* sp1 = sp0 + Cin;
            const float* wp = w_mu + (size_t)((khs[a] * 3 + kws[c]) * Cin) * Cout + cog;
            for (int ci = 0; ci < Cin; ci += 4) {
                const float* wb = wp + (size_t)ci * Cout;
                float4 w0v = *(const float4*)(wb);
                float4 w1v = *(const float4*)(wb + Cout);
                float4 w2v = *(const float4*)(wb + 2 * Cout);
                float4 w3v = *(const float4*)(wb + 3 * Cout);
                float4 u0 = make_float4(w0v.x*w0v.x, w0v.y*w0v.y, w0v.z*w0v.z, w0v.w*w0v.w);
                float4 u1 = make_float4(w1v.x*w1v.x, w1v.y*w1v.y, w1v.z*w1v.z, w1v.w*w1v.w);
                float4 u2 = make_float4(w2v.x*w2v.x, w2v.y*w2v.y, w2v.z*w2v.z, w2v.w*w2v.w);
                float4 u3 = make_float4(w3v.x*w3v.x, w3v.y*w3v.y, w3v.z*w3v.z, w3v.w*w3v.w);
                {
                    float4 m4 = *(const float4*)(mp0 + ci);
                    float4 s4 = *(const float4*)(sp0 + ci);
                    amu0.x += m4.x*w0v.x + m4.y*w1v.x + m4.z*w2v.x + m4.w*w3v.x;
                    amu0.y += m4.x*w0v.y + m4.y*w1v.y + m4.z*w2v.y + m4.w*w3v.y;
                    amu0.z += m4.x*w0v.z + m4.y*w1v.z + m4.z*w2v.z + m4.w*w3v.z;
                    amu0.w += m4.x*w0v.w + m4.y*w1v.w + m4.z*w2v.w + m4.w*w3v.w;
                    asa0.x += s4.x*u0.x + s4.y*u1.x + s4.z*u2.x + s4.w*u3.x;
                    asa0.y += s4.x*u0.y + s4.y*u1.y + s4.z*u2.y + s4.w*u3.y;
                    asa0.z += s4.x*u0.z + s4.y*u1.z + s4.z*u2.z + s4.w*u3.z;
                    asa0.w += s4.x*u0.w + s4.y*u1.w + s4.z*u2.w + s4.w*u3.w;
                }
                if (v1) {
                    float4 m4 = *(const float4*)(mp1 + ci);
                    float4 s4 = *(const float4*)(sp1 + ci);
                    amu1.x += m4.x*w0v.x + m4.y*w1v.x + m4.z*w2v.x + m4.w*w3v.x;
                    amu1.y += m4.x*w0v.y + m4.y*w1v.y + m4.z*w2v.y + m4.w*w3v.y;
                    amu1.z += m4.x*w0v.z + m4.y*w1v.z + m4.z*w2v.z + m4.w*w3v.z;
                    amu1.w += m4.x*w0v.w + m4.y*w1v.w + m4.z*w2v.w + m4.w*w3v.w;
                    asa1.x += s4.x*u0.x + s4.y*u1.x + s4.z*u2.x + s4.w*u3.x;
                    asa1.y += s4.x*u0.y + s4.y*u1.y + s4.z*u2.y + s4.w*u3.y;
                    asa1.z += s4.x*u0.z + s4.y*u1.z + s4.z*u2.z + s4.w*u3.z;
                    asa1.w += s4.x*u0.w + s4.y*u1.w + s4.z*u2.w + s4.w*u3.w;
                }
            }
        }
    }
    float4 sg = *(const float4*)(w_sig + cog);
    float sp0v = softplus_f(sg.x), sp1v = softplus_f(sg.y);
    float sp2v = softplus_f(sg.z), sp3v = softplus_f(sg.w);

    {
        float4 so;
        so.x = q0 * sp0v + asa0.x;
        so.y = q0 * sp1v + asa0.y;
        so.z = q0 * sp2v + asa0.z;
        so.w = q0 * sp3v + asa0.w;
        if (!(amu0.x > 0.f)) { amu0.x = 0.f; so.x = 0.f; }
        if (!(amu0.y > 0.f)) { amu0.y = 0.f; so.y = 0.f; }
        if (!(amu0.z > 0.f)) { amu0.z = 0.f; so.z = 0.f; }
        if (!(amu0.w > 0.f)) { amu0.w = 0.f; so.w = 0.f; }
        size_t oidx = ((size_t)(b * Hout + ho) * Wout + w0) * Cout + cog;
        float mus[4] = {amu0.x, amu0.y, amu0.z, amu0.w};
        float sos[4] = {so.x, so.y, so.z, so.w};
#pragma unroll
        for (int i = 0; i < 4; i++) {
            unsigned short mh = f2bf(mus[i]);
            m_h[oidx + i] = mh;
            m_l[oidx + i] = f2bf(mus[i] - bfval(mh));
            unsigned short sh = f2bf(sos[i]);
            s_h[oidx + i] = sh;
            s_l[oidx + i] = f2bf(sos[i] - bfval(sh));
        }
    }
    if (v1) {
        float4 so;
        so.x = q1 * sp0v + asa1.x;
        so.y = q1 * sp1v + asa1.y;
        so.z = q1 * sp2v + asa1.z;
        so.w = q1 * sp3v + asa1.w;
        if (!(amu1.x > 0.f)) { amu1.x = 0.f; so.x = 0.f; }
        if (!(amu1.y > 0.f)) { amu1.y = 0.f; so.y = 0.f; }
        if (!(amu1.z > 0.f)) { amu1.z = 0.f; so.z = 0.f; }
        if (!(amu1.w > 0.f)) { amu1.w = 0.f; so.w = 0.f; }
        size_t oidx = ((size_t)(b * Hout + ho) * Wout + w1) * Cout + cog;
        float mus[4] = {amu1.x, amu1.y, amu1.z, amu1.w};
        float sos[4] = {so.x, so.y, so.z, so.w};
#pragma unroll
        for (int i = 0; i < 4; i++) {
            unsigned short mh = f2bf(mus[i]);
            m_h[oidx + i] = mh;
            m_l[oidx + i] = f2bf(mus[i] - bfval(mh));
            unsigned short sh = f2bf(sos[i]);
            s_h[oidx + i] = sh;
            s_l[oidx + i] = f2bf(sos[i] - bfval(sh));
        }
    }
}

// ---- pool: fp32 mu for argmax; outputs hi/lo mu + gathered hi/lo s
__global__ void pool_kernel(const float* __restrict__ mu_in,
                            const unsigned short* __restrict__ s_h,
                            const unsigned short* __restrict__ s_l,
                            unsigned short* __restrict__ pm_h,
                            unsigned short* __restrict__ pm_l,
                            unsigned short* __restrict__ ps_h,
                            unsigned short* __restrict__ ps_l,
                            int B_, int H, int W, int C)
{
    int Ho = H / 2, Wo = W / 2;
    size_t total = (size_t)B_ * Ho * Wo * C;
    size_t idx = (size_t)blockIdx.x * blockDim.x + threadIdx.x;
    if (idx >= total) return;
    int c = idx % C;
    size_t t = idx / C;
    int w = t % Wo; t /= Wo;
    int h = t % Ho;
    int b = t / Ho;
    size_t i0 = ((size_t)(b * H + 2 * h) * W + 2 * w) * C + c;
    size_t rowStride = (size_t)W * C;
    float m00 = mu_in[i0], m01 = mu_in[i0 + C];
    float m10 = mu_in[i0 + rowStride], m11 = mu_in[i0 + rowStride + C];
    int best = 0; float bm = m00;
    if (m01 > bm) { bm = m01; best = 1; }
    if (m10 > bm) { bm = m10; best = 2; }
    if (m11 > bm) { bm = m11; best = 3; }
    size_t off = (size_t)(best >> 1) * rowStride + (size_t)(best & 1) * C;
    unsigned short mh = f2bf(bm);
    pm_h[idx] = mh;
    pm_l[idx] = f2bf(bm - bfval(mh));
    ps_h[idx] = s_h[i0 + off];
    ps_l[idx] = s_l[i0 + off];
}

// ---- final 1x1 conv_inter + C=2 softmax density prop (fp32 in)
__global__ void final_kernel(const float* __restrict__ mu_in,
                             const float* __restrict__ s_in,
                             const float* __restrict__ w_mu,
                             const float* __restrict__ w_sig,
                             float* __restrict__ out,
                             int B_, int H, int W, int Cin)
{
    int pix = blockIdx.x * blockDim.x + threadIdx.x;
    int total = B_ * H * W;
    if (pix >= total) return;
    const float* mp = mu_in + (size_t)pix * Cin;
    const float* sp = s_in + (size_t)pix * Cin;
    float mu0 = 0.f, mu1 = 0.f, s0a = 0.f, s1a = 0.f, q = 0.f;
    for (int ci = 0; ci < Cin; ci += 4) {
        float4 m = *(const float4*)(mp + ci);
        float4 s = *(const float4*)(sp + ci);
        float4 wa = *(const float4*)(w_mu + ci * 2);
        float4 wb = *(const float4*)(w_mu + ci * 2 + 4);
        mu0 += m.x * wa.x + m.y * wa.z + m.z * wb.x + m.w * wb.z;
        mu1 += m.x * wa.y + m.y * wa.w + m.z * wb.y + m.w * wb.w;
        s0a += s.x * (wa.x * wa.x) + s.y * (wa.z * wa.z) + s.z * (wb.x * wb.x) + s.w * (wb.z * wb.z);
        s1a += s.x * (wa.y * wa.y) + s.y * (wa.w * wa.w) + s.z * (wb.y * wb.y) + s.w * (wb.w * wb.w);
        q += m.x * m.x + s.x + m.y * m.y + s.y + m.z * m.z + s.z + m.w * m.w + s.w;
    }
    float s0 = q * softplus_f(w_sig[0]) + s0a;
    float s1 = q * softplus_f(w_sig[1]) + s1a;
    float mx = fmaxf(mu0, mu1);
    float e0 = expf(mu0 - mx), e1 = expf(mu1 - mx);
    float inv = 1.f / (e0 + e1);
    float p0 = e0 * inv, p1 = e1 * inv;
    float g00 = p0 - p0 * p0, g01 = -p0 * p1;
    float g10 = -p1 * p0,     g11 = p1 - p1 * p1;
    float so0 = g00 * g00 * s0 + g01 * g01 * s1;
    float so1 = g10 * g10 * s0 + g11 * g11 * s1;
    out[(size_t)pix * 2]     = p0;
    out[(size_t)pix * 2 + 1] = p1;
    size_t off = (size_t)total * 2;
    out[off + (size_t)pix * 2]     = so0;
    out[off + (size_t)pix * 2 + 1] = so1;
}

// ---------------------------------------------------------------------------

extern "C" void kernel_launch(void* const* d_in, const int* in_sizes, int n_in,
                              void* d_out, int out_size, void* d_ws, size_t ws_size,
                              hipStream_t stream)
{
    const float* x = (const float*)d_in[0];
    enum { E1A, E1B, E2A, E2B, BA, BB, D2U, D2A, D2B, D1U, D1A, D1B, FIN, NW };
    const float* wmu[NW];
    const float* wsig[NW];
    for (int i = 0; i < NW; i++) {
        wmu[i]  = (const float*)d_in[1 + 2 * i];
        wsig[i] = (const float*)d_in[2 + 2 * i];
    }

    const int B_ = 4;
    float* ws = (float*)d_ws;
    float* M0  = ws;                         // 4194304 fp32 mu scratch
    float* SF  = ws + 4194304;               // 4194304 fp32 s scratch
    float* tq  = ws + 8388608;               // 65536
    float* q9  = ws + 8454144;               // 65536
    float* spb = ws + 8519680;               // 2048
    unsigned short* us = (unsigned short*)(ws + 8521728);
    const size_t NB = 4194304;
    unsigned short* aMh = us;                // A set
    unsigned short* aMl = us + NB;
    unsigned short* aSh = us + 2 * NB;
    unsigned short* aSl = us + 3 * NB;
    unsigned short* bMh = us + 4 * NB;       // B set
    unsigned short* bMl = us + 5 * NB;
    unsigned short* bSh = us + 6 * NB;
    unsigned short* bSl = us + 7 * NB;
    unsigned short* e1Mh = us + 8 * NB;      // E1 skip
    unsigned short* e1Ml = us + 9 * NB;
    unsigned short* e1Sh = us + 10 * NB;
    unsigned short* e1Sl = us + 11 * NB;
    unsigned short* e2Mh = us + 12 * NB;     // E2 skip (2097152 each)
    unsigned short* e2Ml = e2Mh + 2097152;
    unsigned short* e2Sh = e2Ml + 2097152;
    unsigned short* e2Sl = e2Sh + 2097152;
    unsigned short* wTh  = e2Sl + 2097152;   // 1695744 each (9 MFMA layers)
    unsigned short* wTl  = wTh + 1695744;
    unsigned short* wTsq = wTl + 1695744;

    // 9 dense conv layers on MFMA
    const int mlay[9]  = {E1B, E2A, E2B, BA, BB, D2A, D2B, D1A, D1B};
    const int mcin[9]  = {64, 64, 128, 128, 256, 256, 128, 128, 64};
    const int mcout[9] = {64, 128, 128, 256, 256, 128, 128, 64, 64};
    size_t woff[NW]; int spoff[NW];
    {
        size_t wo = 0; int so = 0;
        for (int i = 0; i < 9; i++) {
            int l = mlay[i];
            woff[l] = wo; spoff[l] = so;
            int n = 9 * mcin[i] * mcout[i];
            wprep3_kernel<<<dim3((n + 255) / 256), dim3(256), 0, stream>>>(
                wmu[l], wTh + wo, wTl + wo, wTsq + wo, mcin[i], mcout[i], n);
            sp_kernel<<<dim3(1), dim3(256), 0, stream>>>(wsig[l], spb + so, mcout[i]);
            wo += n; so += mcout[i];
        }
    }

    // dense fused MFMA layer: t_hl + q9 + fused conv
    auto flayer = [&](const unsigned short* i_mh, const unsigned short* i_ml,
                      const unsigned short* i_sh, const unsigned short* i_sl, int ci1,
                      const unsigned short* k_mh, const unsigned short* k_ml,
                      const unsigned short* k_sh, const unsigned short* k_sl,
                      int ci2, int h2, int w2, int dh, int dw,
                      int H, int W, int widx, int cout,
                      float* oMf, float* oSf,
                      unsigned short* oMh, unsigned short* oMl,
                      unsigned short* oSh, unsigned short* oSl) {
        int total = B_ * H * W;
        t_hl_kernel<<<dim3((total + 255) / 256), dim3(256), 0, stream>>>(
            i_mh, i_ml, i_sh, i_sl, k_mh, k_ml, k_sh, k_sl, tq,
            B_, H, W, ci1, ci2, h2, w2, dh, dw);
        q9_kernel<<<dim3((total + 255) / 256), dim3(256), 0, stream>>>(tq, q9, B_, H, W);
        fused_layer_kernel<<<dim3((total + 63) / 64, cout / 64), dim3(256), 0, stream>>>(
            i_mh, i_ml, i_sh, i_sl, k_mh, k_ml, k_sh, k_sl, q9,
            wTh + woff[widx], wTl + woff[widx], wTsq + woff[widx], spb + spoff[widx],
            oMf, oSf, oMh, oMl, oSh, oSl,
            B_, H, W, ci1, ci2, h2, w2, dh, dw, cout);
    };

    // vector unpool layer (exact fp32 gates), pair-blocked
    auto unpool = [&](const float* mi, const float* si,
                      int hi, int wi, int ci, int ho, int wo, int co, int widx,
                      unsigned short* oMh, unsigned short* oMl,
                      unsigned short* oSh, unsigned short* oSl) {
        int nin = B_ * hi * wi;
        t_f32_kernel<<<dim3((nin + 255) / 256), dim3(256), 0, stream>>>(mi, si, tq, nin, ci);
        int Wp = 2 * ((wo + 3) / 4);
        int totalP = B_ * ho * Wp;
        int tx = co / 4, ty = 256 / tx;
        conv_unpool_pair<<<dim3((totalP + ty - 1) / ty), dim3(tx, ty), 0, stream>>>(
            mi, si, tq, wmu[widx], wsig[widx], oMh, oMl, oSh, oSl,
            B_, hi, wi, ci, ho, wo, co);
    };

    // ---- encoder level 1 ----
    {
        int totalPix = B_ * 128 * 128;
        conv_input_relu_kernel<<<dim3((totalPix + 3) / 4), dim3(64, 4), 0, stream>>>(
            x, wmu[E1A], wsig[E1A], aMh, aMl, aSh, aSl, B_, 128, 128, 3, 64);
    }
    // E1B: A -> E1 skip (hi/lo) + fp32 mu (M0) for pool argmax
    flayer(aMh, aMl, aSh, aSl, 64, nullptr, nullptr, nullptr, nullptr, 0, 0, 0, 0, 0,
           128, 128, E1B, 64, M0, nullptr, e1Mh, e1Ml, e1Sh, e1Sl);
    {
        size_t total = (size_t)B_ * 64 * 64 * 64;
        pool_kernel<<<dim3((total + 255) / 256), dim3(256), 0, stream>>>(
            M0, e1Sh, e1Sl, bMh, bMl, bSh, bSl, B_, 128, 128, 64);
    }
    // ---- encoder level 2 ----
    flayer(bMh, bMl, bSh, bSl, 64, nullptr, nullptr, nullptr, nullptr, 0, 0, 0, 0, 0,
           64, 64, E2A, 128, nullptr, nullptr, aMh, aMl, aSh, aSl);
    flayer(aMh, aMl, aSh, aSl, 128, nullptr, nullptr, nullptr, nullptr, 0, 0, 0, 0, 0,
           64, 64, E2B, 128, M0, nullptr, e2Mh, e2Ml, e2Sh, e2Sl);
    {
        size_t total = (size_t)B_ * 32 * 32 * 128;
        pool_kernel<<<dim3((total + 255) / 256), dim3(256), 0, stream>>>(
            M0, e2Sh, e2Sl, bMh, bMl, bSh, bSl, B_, 64, 64, 128);
    }
    // ---- bottleneck ----
    flayer(bMh, bMl, bSh, bSl, 128, nullptr, nullptr, nullptr, nullptr, 0, 0, 0, 0, 0,
           32, 32, BA, 256, nullptr, nullptr, aMh, aMl, aSh, aSl);
    flayer(aMh, aMl, aSh, aSl, 256, nullptr, nullptr, nullptr, nullptr, 0, 0, 0, 0, 0,
           32, 32, BB, 256, M0, SF, nullptr, nullptr, nullptr, nullptr);
    // ---- decoder level 2 ----
    unpool(M0, SF, 32, 32, 256, 63, 63, 128, D2U, bMh, bMl, bSh, bSl);
    flayer(bMh, bMl, bSh, bSl, 128, e2Mh, e2Ml, e2Sh, e2Sl, 128, 64, 64, 0, 0,
           63, 63, D2A, 128, nullptr, nullptr, aMh, aMl, aSh, aSl);
    flayer(aMh, aMl, aSh, aSl, 128, nullptr, nullptr, nullptr, nullptr, 0, 0, 0, 0, 0,
           63, 63, D2B, 128, M0, SF, nullptr, nullptr, nullptr, nullptr);
    // ---- decoder level 1 ----
    unpool(M0, SF, 63, 63, 128, 125, 125, 64, D1U, bMh, bMl, bSh, bSl);
    flayer(bMh, bMl, bSh, bSl, 64, e1Mh, e1Ml, e1Sh, e1Sl, 64, 128, 128, 1, 1,
           125, 125, D1A, 64, nullptr, nullptr, aMh, aMl, aSh, aSl);
    flayer(aMh, aMl, aSh, aSl, 64, nullptr, nullptr, nullptr, nullptr, 0, 0, 0, 0, 0,
           125, 125, D1B, 64, M0, SF, nullptr, nullptr, nullptr, nullptr);
    // ---- final 1x1 + softmax prop ----
    {
        int totalPix = B_ * 125 * 125;
        final_kernel<<<dim3((totalPix + 63) / 64), dim3(64), 0, stream>>>(
            M0, SF, wmu[FIN], wsig[FIN], (float*)d_out, B_, 125, 125, 64);
    }
}

// Round 12
// 2226.943 us; speedup vs baseline: 1.9157x; 1.0275x over previous
//
#include <hip/hip_runtime.h>
#include <math.h>

// ---------------------------------------------------------------------------
// Variance-propagating UNet (density prop), NHWC.
// Round 12: round-11 numerics unchanged (absmax 6144). Single change:
// XCD-aware block swizzle in fused_layer_kernel. Round-11 PMC showed 278 MB
// FETCH vs 32 MB unique input (~8.7x = 9 taps x 8 XCDs): linear pixel-block
// order round-robined across XCDs made every per-XCD L2 stream the whole
// tensor. Now each XCD gets a contiguous pixel slab (all cout tiles).
// ---------------------------------------------------------------------------

typedef __attribute__((ext_vector_type(8))) short short8;
typedef __attribute__((ext_vector_type(4))) float floatx4;

__device__ __forceinline__ float softplus_f(float x) { return log1pf(expf(x)); }

__device__ __forceinline__ unsigned short f2bf(float x) {
    unsigned int u = __float_as_uint(x);
    u = (u + 0x7FFF + ((u >> 16) & 1)) >> 16;
    return (unsigned short)u;
}
__device__ __forceinline__ float bfval(unsigned short h) {
    return __uint_as_float((unsigned int)h << 16);
}
__device__ __forceinline__ float bf2f_lo(unsigned int u) {
    return __uint_as_float(u << 16);
}
__device__ __forceinline__ float bf2f_hi(unsigned int u) {
    return __uint_as_float(u & 0xFFFF0000u);
}

// ---- weight prep: transposed [tap][co][ci]; w hi, w lo, w^2 (bf16)
__global__ void wprep3_kernel(const float* __restrict__ w,
                              unsigned short* __restrict__ wTh,
                              unsigned short* __restrict__ wTl,
                              unsigned short* __restrict__ wTsq,
                              int Cin, int Cout, int n)
{
    int idx = blockIdx.x * blockDim.x + threadIdx.x;
    if (idx >= n) return;
    int per = Cin * Cout;
    int tap = idx / per;
    int rem = idx - tap * per;
    int co = rem / Cin;
    int ci = rem - co * Cin;
    float v = w[(size_t)(tap * Cin + ci) * Cout + co];
    unsigned short hh = f2bf(v);
    wTh[idx] = hh;
    wTl[idx] = f2bf(v - bfval(hh));
    wTsq[idx] = f2bf(v * v);
}

__global__ void sp_kernel(const float* __restrict__ wsig,
                          float* __restrict__ sp, int n)
{
    int i = blockIdx.x * blockDim.x + threadIdx.x;
    if (i < n) sp[i] = softplus_f(wsig[i]);
}

// ---- t from hi/lo mu + hi/lo s (optional 2nd source at crop offset)
__global__ void t_hl_kernel(const unsigned short* __restrict__ m1h,
                            const unsigned short* __restrict__ m1l,
                            const unsigned short* __restrict__ s1h,
                            const unsigned short* __restrict__ s1l,
                            const unsigned short* __restrict__ m2h,
                            const unsigned short* __restrict__ m2l,
                            const unsigned short* __restrict__ s2h,
                            const unsigned short* __restrict__ s2l,
                            float* __restrict__ t_out,
                            int B_, int Hin, int Win, int Cin1, int Cin2,
                            int H2, int W2, int dh, int dw)
{
    int pix = blockIdx.x * blockDim.x + threadIdx.x;
    int total = B_ * Hin * Win;
    if (pix >= total) return;
    float acc = 0.f;
    {
        const unsigned short* mh = m1h + (size_t)pix * Cin1;
        const unsigned short* ml = m1l + (size_t)pix * Cin1;
        const unsigned short* sh = s1h + (size_t)pix * Cin1;
        const unsigned short* sl = s1l + (size_t)pix * Cin1;
        for (int ci = 0; ci < Cin1; ci += 8) {
            uint4 vmh = *(const uint4*)(mh + ci);
            uint4 vml = *(const uint4*)(ml + ci);
            uint4 vsh = *(const uint4*)(sh + ci);
            uint4 vsl = *(const uint4*)(sl + ci);
            float m0 = bf2f_lo(vmh.x) + bf2f_lo(vml.x), m1 = bf2f_hi(vmh.x) + bf2f_hi(vml.x);
            float m2 = bf2f_lo(vmh.y) + bf2f_lo(vml.y), m3 = bf2f_hi(vmh.y) + bf2f_hi(vml.y);
            float m4 = bf2f_lo(vmh.z) + bf2f_lo(vml.z), m5 = bf2f_hi(vmh.z) + bf2f_hi(vml.z);
            float m6 = bf2f_lo(vmh.w) + bf2f_lo(vml.w), m7 = bf2f_hi(vmh.w) + bf2f_hi(vml.w);
            acc += m0*m0 + m1*m1 + m2*m2 + m3*m3 + m4*m4 + m5*m5 + m6*m6 + m7*m7;
            acc += bf2f_lo(vsh.x) + bf2f_hi(vsh.x) + bf2f_lo(vsh.y) + bf2f_hi(vsh.y)
                 + bf2f_lo(vsh.z) + bf2f_hi(vsh.z) + bf2f_lo(vsh.w) + bf2f_hi(vsh.w);
            acc += bf2f_lo(vsl.x) + bf2f_hi(vsl.x) + bf2f_lo(vsl.y) + bf2f_hi(vsl.y)
                 + bf2f_lo(vsl.z) + bf2f_hi(vsl.z) + bf2f_lo(vsl.w) + bf2f_hi(vsl.w);
        }
    }
    if (Cin2 > 0) {
        int b = pix / (Hin * Win);
        int rem = pix - b * (Hin * Win);
        int h = rem / Win, w = rem - (rem / Win) * Win;
        size_t base = ((size_t)(b * H2 + h + dh) * W2 + (w + dw)) * Cin2;
        const unsigned short* mh = m2h + base;
        const unsigned short* ml = m2l + base;
        const unsigned short* sh = s2h + base;
        const unsigned short* sl = s2l + base;
        for (int ci = 0; ci < Cin2; ci += 8) {
            uint4 vmh = *(const uint4*)(mh + ci);
            uint4 vml = *(const uint4*)(ml + ci);
            uint4 vsh = *(const uint4*)(sh + ci);
            uint4 vsl = *(const uint4*)(sl + ci);
            float m0 = bf2f_lo(vmh.x) + bf2f_lo(vml.x), m1 = bf2f_hi(vmh.x) + bf2f_hi(vml.x);
            float m2 = bf2f_lo(vmh.y) + bf2f_lo(vml.y), m3 = bf2f_hi(vmh.y) + bf2f_hi(vml.y);
            float m4 = bf2f_lo(vmh.z) + bf2f_lo(vml.z), m5 = bf2f_hi(vmh.z) + bf2f_hi(vml.z);
            float m6 = bf2f_lo(vmh.w) + bf2f_lo(vml.w), m7 = bf2f_hi(vmh.w) + bf2f_hi(vml.w);
            acc += m0*m0 + m1*m1 + m2*m2 + m3*m3 + m4*m4 + m5*m5 + m6*m6 + m7*m7;
            acc += bf2f_lo(vsh.x) + bf2f_hi(vsh.x) + bf2f_lo(vsh.y) + bf2f_hi(vsh.y)
                 + bf2f_lo(vsh.z) + bf2f_hi(vsh.z) + bf2f_lo(vsh.w) + bf2f_hi(vsh.w);
            acc += bf2f_lo(vsl.x) + bf2f_hi(vsl.x) + bf2f_lo(vsl.y) + bf2f_hi(vsl.y)
                 + bf2f_lo(vsl.z) + bf2f_hi(vsl.z) + bf2f_lo(vsl.w) + bf2f_hi(vsl.w);
        }
    }
    t_out[pix] = acc;
}

// ---- t from fp32 mu + fp32 s (for unpool-conv inputs)
__global__ void t_f32_kernel(const float* __restrict__ mu1, const float* __restrict__ s1,
                             float* __restrict__ t_out, int total, int Cin)
{
    int pix = blockIdx.x * blockDim.x + threadIdx.x;
    if (pix >= total) return;
    const float* mp = mu1 + (size_t)pix * Cin;
    const float* sp = s1 + (size_t)pix * Cin;
    float acc = 0.f;
    for (int ci = 0; ci < Cin; ci += 4) {
        float4 m = *(const float4*)(mp + ci);
        float4 s = *(const float4*)(sp + ci);
        acc += m.x * m.x + s.x + m.y * m.y + s.y
             + m.z * m.z + s.z + m.w * m.w + s.w;
    }
    t_out[pix] = acc;
}

// ---- q9: sum t over valid 3x3 taps (pad=1)
__global__ void q9_kernel(const float* __restrict__ t_in,
                          float* __restrict__ q9, int B_, int H, int W)
{
    int pix = blockIdx.x * blockDim.x + threadIdx.x;
    int total = B_ * H * W;
    if (pix >= total) return;
    int b = pix / (H * W);
    int rem = pix - b * (H * W);
    int h = rem / W, w = rem - (rem / W) * W;
    float acc = 0.f;
    for (int kh = 0; kh < 3; kh++) {
        int ih = h + kh - 1;
        if ((unsigned)ih >= (unsigned)H) continue;
        for (int kw = 0; kw < 3; kw++) {
            int iw = w + kw - 1;
            if ((unsigned)iw >= (unsigned)W) continue;
            acc += t_in[(size_t)(b * H + ih) * W + iw];
        }
    }
    q9[pix] = acc;
}

// ---- FUSED MFMA layer (dense convs): mu (3-MFMA split) + s (2-MFMA hi/lo)
// + relu gate from the fp32 accumulator. Each wave: 16 pixels x 64 cout.
// 1D grid (padded to x8) with XCD swizzle: gid = (bid&7)*chunk + (bid>>3);
// gid = pixBlk*ntiles + coTile -> each XCD gets a contiguous pixel slab.
__global__ void __launch_bounds__(256)
fused_layer_kernel(const unsigned short* __restrict__ m1h, const unsigned short* __restrict__ m1l,
                   const unsigned short* __restrict__ s1h, const unsigned short* __restrict__ s1l,
                   const unsigned short* __restrict__ m2h, const unsigned short* __restrict__ m2l,
                   const unsigned short* __restrict__ s2h, const unsigned short* __restrict__ s2l,
                   const float* __restrict__ q9v,
                   const unsigned short* __restrict__ wTh, const unsigned short* __restrict__ wTl,
                   const unsigned short* __restrict__ wTsq,
                   const float* __restrict__ spv_,
                   float* __restrict__ oMf, float* __restrict__ oSf,
                   unsigned short* __restrict__ oMh, unsigned short* __restrict__ oMl,
                   unsigned short* __restrict__ oSh, unsigned short* __restrict__ oSl,
                   int B_, int H, int W, int Cin1, int Cin2,
                   int H2, int W2, int dh, int dw, int Cout)
{
    const int lane = threadIdx.x & 63;
    const int wave = threadIdx.x >> 6;
    const int total = B_ * H * W;
    const int Cin = Cin1 + Cin2;
    const int ntiles = Cout >> 6;
    const int nPixBlk = (total + 63) >> 6;
    const int nReal = nPixBlk * ntiles;
    // XCD swizzle (gridDim.x is a multiple of 8)
    const int chunk = (int)gridDim.x >> 3;
    int gid = ((int)blockIdx.x & 7) * chunk + ((int)blockIdx.x >> 3);
    if (gid >= nReal) return;
    const int coTile = gid % ntiles;
    const int pixBlk = gid / ntiles;
    const int pixBase = pixBlk * 64 + wave * 16;
    const int coBase = coTile * 64;
    const int row = lane & 15;
    const int quad = lane >> 4;

    int P = pixBase + row;
    bool pv = P < total;
    int Pc = pv ? P : 0;
    int pb = Pc / (H * W);
    int r0i = Pc - pb * (H * W);
    int ph = r0i / W;
    int pw = r0i - ph * W;

    floatx4 accM[4], accS[4];
#pragma unroll
    for (int i = 0; i < 4; i++) {
        accM[i] = (floatx4){0.f, 0.f, 0.f, 0.f};
        accS[i] = (floatx4){0.f, 0.f, 0.f, 0.f};
    }
    const short8 zero8 = {0, 0, 0, 0, 0, 0, 0, 0};

    for (int tap = 0; tap < 9; tap++) {
        int kh = tap / 3, kw = tap - kh * 3;
        int ih = ph + kh - 1, iw = pw + kw - 1;
        bool tv = pv && ((unsigned)ih < (unsigned)H) && ((unsigned)iw < (unsigned)W);
        if (!tv) { ih = 0; iw = 0; }
        // source 1
        {
            size_t ab = ((size_t)(pb * H + ih) * W + iw) * (size_t)Cin1 + quad * 8;
            const size_t wbase = (size_t)(tap * Cout + coBase) * Cin + quad * 8;
            for (int kb = 0; kb < Cin1; kb += 32) {
                short8 aMh = zero8, aMl = zero8, aSh = zero8, aSl = zero8;
                if (tv) {
                    aMh = *(const short8*)(m1h + ab + kb);
                    aMl = *(const short8*)(m1l + ab + kb);
                    aSh = *(const short8*)(s1h + ab + kb);
                    aSl = *(const short8*)(s1l + ab + kb);
                }
#pragma unroll
                for (int nt = 0; nt < 4; nt++) {
                    size_t wo = wbase + (size_t)(nt * 16 + row) * Cin + kb;
                    short8 bh = *(const short8*)(wTh + wo);
                    short8 bl = *(const short8*)(wTl + wo);
                    short8 bq = *(const short8*)(wTsq + wo);
                    accM[nt] = __builtin_amdgcn_mfma_f32_16x16x32_bf16(aMh, bh, accM[nt], 0, 0, 0);
                    accM[nt] = __builtin_amdgcn_mfma_f32_16x16x32_bf16(aMl, bh, accM[nt], 0, 0, 0);
                    accM[nt] = __builtin_amdgcn_mfma_f32_16x16x32_bf16(aMh, bl, accM[nt], 0, 0, 0);
                    accS[nt] = __builtin_amdgcn_mfma_f32_16x16x32_bf16(aSh, bq, accS[nt], 0, 0, 0);
                    accS[nt] = __builtin_amdgcn_mfma_f32_16x16x32_bf16(aSl, bq, accS[nt], 0, 0, 0);
                }
            }
        }
        // source 2 (fused skip concat)
        if (Cin2 > 0) {
            size_t ab = ((size_t)(pb * H2 + ih + dh) * W2 + (iw + dw)) * (size_t)Cin2 + quad * 8;
            const size_t wbase = (size_t)(tap * Cout + coBase) * Cin + Cin1 + quad * 8;
            for (int kb = 0; kb < Cin2; kb += 32) {
                short8 aMh = zero8, aMl = zero8, aSh = zero8, aSl = zero8;
                if (tv) {
                    aMh = *(const short8*)(m2h + ab + kb);
                    aMl = *(const short8*)(m2l + ab + kb);
                    aSh = *(const short8*)(s2h + ab + kb);
                    aSl = *(const short8*)(s2l + ab + kb);
                }
#pragma unroll
                for (int nt = 0; nt < 4; nt++) {
                    size_t wo = wbase + (size_t)(nt * 16 + row) * Cin + kb;
                    short8 bh = *(const short8*)(wTh + wo);
                    short8 bl = *(const short8*)(wTl + wo);
                    short8 bq = *(const short8*)(wTsq + wo);
                    accM[nt] = __builtin_amdgcn_mfma_f32_16x16x32_bf16(aMh, bh, accM[nt], 0, 0, 0);
                    accM[nt] = __builtin_amdgcn_mfma_f32_16x16x32_bf16(aMl, bh, accM[nt], 0, 0, 0);
                    accM[nt] = __builtin_amdgcn_mfma_f32_16x16x32_bf16(aMh, bl, accM[nt], 0, 0, 0);
                    accS[nt] = __builtin_amdgcn_mfma_f32_16x16x32_bf16(aSh, bq, accS[nt], 0, 0, 0);
                    accS[nt] = __builtin_amdgcn_mfma_f32_16x16x32_bf16(aSl, bq, accS[nt], 0, 0, 0);
                }
            }
        }
    }

#pragma unroll
    for (int nt = 0; nt < 4; nt++) {
        int co = coBase + nt * 16 + row;
        float spv = spv_[co];
        floatx4 am = accM[nt];
        floatx4 as = accS[nt];
#pragma unroll
        for (int r = 0; r < 4; r++) {
            int P2 = pixBase + quad * 4 + r;
            if (P2 < total) {
                size_t o = (size_t)P2 * Cout + co;
                float mu = am[r];
                float s = q9v[P2] * spv + as[r];
                if (!(mu > 0.f)) { mu = 0.f; s = 0.f; }
                if (oMf) oMf[o] = mu;
                if (oSf) oSf[o] = s;
                if (oMh) {
                    unsigned short mh = f2bf(mu);
                    oMh[o] = mh;
                    oMl[o] = f2bf(mu - bfval(mh));
                    unsigned short sh = f2bf(s);
                    oSh[o] = sh;
                    oSl[o] = f2bf(s - bfval(sh));
                }
            }
        }
    }
}

// ---- first layer (Cin=3): hi/lo outputs
__global__ void conv_input_relu_kernel(const float* __restrict__ x,
                                       const float* __restrict__ w_mu,
                                       const float* __restrict__ w_sig,
                                       unsigned short* __restrict__ m_h,
                                       unsigned short* __restrict__ m_l,
                                       unsigned short* __restrict__ s_h,
                                       unsigned short* __restrict__ s_l,
                                       int B_, int H, int W, int Cin, int Cout)
{
    int co = threadIdx.x;
    int pix = blockIdx.x * blockDim.y + threadIdx.y;
    int total = B_ * H * W;
    if (pix >= total) return;
    int b = pix / (H * W);
    int rem = pix % (H * W);
    int h = rem / W, w = rem % W;

    float mu = 0.f, q = 0.f;
    for (int kh = 0; kh < 3; kh++) {
        int ih = h + kh - 1;
        if (ih < 0 || ih >= H) continue;
        for (int kw = 0; kw < 3; kw++) {
            int iw = w + kw - 1;
            if (iw < 0 || iw >= W) continue;
            const float* xp = x + ((size_t)(b * H + ih) * W + iw) * Cin;
            const float* wp = w_mu + (size_t)((kh * 3 + kw) * Cin) * Cout + co;
            for (int ci = 0; ci < Cin; ci++) {
                float xv = xp[ci];
                mu += xv * wp[(size_t)ci * Cout];
                q += xv * xv;
            }
        }
    }
    float s = q * softplus_f(w_sig[co]);
    if (!(mu > 0.f)) { mu = 0.f; s = 0.f; }
    size_t oidx = (size_t)pix * Cout + co;
    unsigned short mh = f2bf(mu);
    m_h[oidx] = mh;
    m_l[oidx] = f2bf(mu - bfval(mh));
    unsigned short sh = f2bf(s);
    s_h[oidx] = sh;
    s_l[oidx] = f2bf(s - bfval(sh));
}

// ---- unpool+conv (fp32 vector, exact gates): 2 SAME-PARITY pixels per
// thread (wo, wo+2) — identical live-tap sets, weight loads + w^2 shared.
__global__ void __launch_bounds__(256)
conv_unpool_pair(const float* __restrict__ mu_in,
                 const float* __restrict__ s_in,
                 const float* __restrict__ tq,
                 const float* __restrict__ w_mu,
                 const float* __restrict__ w_sig,
                 unsigned short* __restrict__ m_h,
                 unsigned short* __restrict__ m_l,
                 unsigned short* __restrict__ s_h,
                 unsigned short* __restrict__ s_l,
                 int B_, int Hin, int Win, int Cin,
                 int Hout, int Wout, int Cout)
{
    int cog = threadIdx.x * 4;
    const int Wp = 2 * ((Wout + 3) >> 2);   // pair slots per row
    int pr = blockIdx.x * blockDim.y + threadIdx.y;
    int totalP = B_ * Hout * Wp;
    if (pr >= totalP) return;
    int b = pr / (Hout * Wp);
    int rem = pr - b * (Hout * Wp);
    int ho = rem / Wp;
    int k = rem - ho * Wp;
    int w0 = 4 * (k >> 1) + (k & 1);
    if (w0 >= Wout) return;
    int w1 = w0 + 2;
    const bool v1 = w1 < Wout;

    int khs[2], ihs[2], nkh;
    if (ho & 1) { nkh = 2; khs[0] = 0; ihs[0] = (ho - 1) >> 1; khs[1] = 2; ihs[1] = (ho + 1) >> 1; }
    else        { nkh = 1; khs[0] = 1; ihs[0] = ho >> 1; }
    int kws[2], iws[2], nkw;
    if (w0 & 1) { nkw = 2; kws[0] = 0; iws[0] = (w0 - 1) >> 1; kws[1] = 2; iws[1] = (w0 + 1) >> 1; }
    else        { nkw = 1; kws[0] = 1; iws[0] = w0 >> 1; }

    float4 amu0 = make_float4(0.f, 0.f, 0.f, 0.f);
    float4 asa0 = make_float4(0.f, 0.f, 0.f, 0.f);
    float4 amu1 = make_float4(0.f, 0.f, 0.f, 0.f);
    float4 asa1 = make_float4(0.f, 0.f, 0.f, 0.f);
    float q0 = 0.f, q1 = 0.f;

    for (int a = 0; a < nkh; a++) {
        for (int c = 0; c < nkw; c++) {
            size_t trow = (size_t)(b * Hin + ihs[a]) * Win + iws[c];
            q0 += tq[trow];
            if (v1) q1 += tq[trow + 1];
            size_t base0 = trow * Cin;
            const float* mp0 = mu_in + base0;
            const float* sp0 = s_in + base0;
            const float* mp1 = mp0 + Cin;
            const float* sp1 = sp0 + Cin;
            const float* wp = w_mu + (size_t)((khs[a] * 3 + kws[c]) * Cin) * Cout + cog;
            for (int ci = 0; ci < Cin; ci += 4) {
                const float* wb = wp + (size_t)ci * Cout;
                float4 w0v = *(const float4*)(wb);
                float4 w1v = *(const float4*)(wb + Cout);
                float4 w2v = *(const float4*)(wb + 2 * Cout);
                float4 w3v = *(const float4*)(wb + 3 * Cout);
                float4 u0 = make_float4(w0v.x*w0v.x, w0v.y*w0v.y, w0v.z*w0v.z, w0v.w*w0v.w);
                float4 u1 = make_float4(w1v.x*w1v.x, w1v.y*w1v.y, w1v.z*w1v.z, w1v.w*w1v.w);
                float4 u2 = make_float4(w2v.x*w2v.x, w2v.y*w2v.y, w2v.z*w2v.z, w2v.w*w2v.w);
                float4 u3 = make_float4(w3v.x*w3v.x, w3v.y*w3v.y, w3v.z*w3v.z, w3v.w*w3v.w);
                {
                    float4 m4 = *(const float4*)(mp0 + ci);
                    float4 s4 = *(const float4*)(sp0 + ci);
                    amu0.x += m4.x*w0v.x + m4.y*w1v.x + m4.z*w2v.x + m4.w*w3v.x;
                    amu0.y += m4.x*w0v.y + m4.y*w1v.y + m4.z*w2v.y + m4.w*w3v.y;
                    amu0.z += m4.x*w0v.z + m4.y*w1v.z + m4.z*w2v.z + m4.w*w3v.z;
                    amu0.w += m4.x*w0v.w + m4.y*w1v.w + m4.z*w2v.w + m4.w*w3v.w;
                    asa0.x += s4.x*u0.x + s4.y*u1.x + s4.z*u2.x + s4.w*u3.x;
                    asa0.y += s4.x*u0.y + s4.y*u1.y + s4.z*u2.y + s4.w*u3.y;
                    asa0.z += s4.x*u0.z + s4.y*u1.z + s4.z*u2.z + s4.w*u3.z;
                    asa0.w += s4.x*u0.w + s4.y*u1.w + s4.z*u2.w + s4.w*u3.w;
                }
                if (v1) {
                    float4 m4 = *(const float4*)(mp1 + ci);
                    float4 s4 = *(const float4*)(sp1 + ci);
                    amu1.x += m4.x*w0v.x + m4.y*w1v.x + m4.z*w2v.x + m4.w*w3v.x;
                    amu1.y += m4.x*w0v.y + m4.y*w1v.y + m4.z*w2v.y + m4.w*w3v.y;
                    amu1.z += m4.x*w0v.z + m4.y*w1v.z + m4.z*w2v.z + m4.w*w3v.z;
                    amu1.w += m4.x*w0v.w + m4.y*w1v.w + m4.z*w2v.w + m4.w*w3v.w;
                    asa1.x += s4.x*u0.x + s4.y*u1.x + s4.z*u2.x + s4.w*u3.x;
                    asa1.y += s4.x*u0.y + s4.y*u1.y + s4.z*u2.y + s4.w*u3.y;
                    asa1.z += s4.x*u0.z + s4.y*u1.z + s4.z*u2.z + s4.w*u3.z;
                    asa1.w += s4.x*u0.w + s4.y*u1.w + s4.z*u2.w + s4.w*u3.w;
                }
            }
        }
    }
    float4 sg = *(const float4*)(w_sig + cog);
    float sp0v = softplus_f(sg.x), sp1v = softplus_f(sg.y);
    float sp2v = softplus_f(sg.z), sp3v = softplus_f(sg.w);

    {
        float4 so;
        so.x = q0 * sp0v + asa0.x;
        so.y = q0 * sp1v + asa0.y;
        so.z = q0 * sp2v + asa0.z;
        so.w = q0 * sp3v + asa0.w;
        if (!(amu0.x > 0.f)) { amu0.x = 0.f; so.x = 0.f; }
        if (!(amu0.y > 0.f)) { amu0.y = 0.f; so.y = 0.f; }
        if (!(amu0.z > 0.f)) { amu0.z = 0.f; so.z = 0.f; }
        if (!(amu0.w > 0.f)) { amu0.w = 0.f; so.w = 0.f; }
        size_t oidx = ((size_t)(b * Hout + ho) * Wout + w0) * Cout + cog;
        float mus[4] = {amu0.x, amu0.y, amu0.z, amu0.w};
        float sos[4] = {so.x, so.y, so.z, so.w};
#pragma unroll
        for (int i = 0; i < 4; i++) {
            unsigned short mh = f2bf(mus[i]);
            m_h[oidx + i] = mh;
            m_l[oidx + i] = f2bf(mus[i] - bfval(mh));
            unsigned short sh = f2bf(sos[i]);
            s_h[oidx + i] = sh;
            s_l[oidx + i] = f2bf(sos[i] - bfval(sh));
        }
    }
    if (v1) {
        float4 so;
        so.x = q1 * sp0v + asa1.x;
        so.y = q1 * sp1v + asa1.y;
        so.z = q1 * sp2v + asa1.z;
        so.w = q1 * sp3v + asa1.w;
        if (!(amu1.x > 0.f)) { amu1.x = 0.f; so.x = 0.f; }
        if (!(amu1.y > 0.f)) { amu1.y = 0.f; so.y = 0.f; }
        if (!(amu1.z > 0.f)) { amu1.z = 0.f; so.z = 0.f; }
        if (!(amu1.w > 0.f)) { amu1.w = 0.f; so.w = 0.f; }
        size_t oidx = ((size_t)(b * Hout + ho) * Wout + w1) * Cout + cog;
        float mus[4] = {amu1.x, amu1.y, amu1.z, amu1.w};
        float sos[4] = {so.x, so.y, so.z, so.w};
#pragma unroll
        for (int i = 0; i < 4; i++) {
            unsigned short mh = f2bf(mus[i]);
            m_h[oidx + i] = mh;
            m_l[oidx + i] = f2bf(mus[i] - bfval(mh));
            unsigned short sh = f2bf(sos[i]);
            s_h[oidx + i] = sh;
            s_l[oidx + i] = f2bf(sos[i] - bfval(sh));
        }
    }
}

// ---- pool: fp32 mu for argmax; outputs hi/lo mu + gathered hi/lo s
__global__ void pool_kernel(const float* __restrict__ mu_in,
                            const unsigned short* __restrict__ s_h,
                            const unsigned short* __restrict__ s_l,
                            unsigned short* __restrict__ pm_h,
                            unsigned short* __restrict__ pm_l,
                            unsigned short* __restrict__ ps_h,
                            unsigned short* __restrict__ ps_l,
                            int B_, int H, int W, int C)
{
    int Ho = H / 2, Wo = W / 2;
    size_t total = (size_t)B_ * Ho * Wo * C;
    size_t idx = (size_t)blockIdx.x * blockDim.x + threadIdx.x;
    if (idx >= total) return;
    int c = idx % C;
    size_t t = idx / C;
    int w = t % Wo; t /= Wo;
    int h = t % Ho;
    int b = t / Ho;
    size_t i0 = ((size_t)(b * H + 2 * h) * W + 2 * w) * C + c;
    size_t rowStride = (size_t)W * C;
    float m00 = mu_in[i0], m01 = mu_in[i0 + C];
    float m10 = mu_in[i0 + rowStride], m11 = mu_in[i0 + rowStride + C];
    int best = 0; float bm = m00;
    if (m01 > bm) { bm = m01; best = 1; }
    if (m10 > bm) { bm = m10; best = 2; }
    if (m11 > bm) { bm = m11; best = 3; }
    size_t off = (size_t)(best >> 1) * rowStride + (size_t)(best & 1) * C;
    unsigned short mh = f2bf(bm);
    pm_h[idx] = mh;
    pm_l[idx] = f2bf(bm - bfval(mh));
    ps_h[idx] = s_h[i0 + off];
    ps_l[idx] = s_l[i0 + off];
}

// ---- final 1x1 conv_inter + C=2 softmax density prop (fp32 in)
__global__ void final_kernel(const float* __restrict__ mu_in,
                             const float* __restrict__ s_in,
                             const float* __restrict__ w_mu,
                             const float* __restrict__ w_sig,
                             float* __restrict__ out,
                             int B_, int H, int W, int Cin)
{
    int pix = blockIdx.x * blockDim.x + threadIdx.x;
    int total = B_ * H * W;
    if (pix >= total) return;
    const float* mp = mu_in + (size_t)pix * Cin;
    const float* sp = s_in + (size_t)pix * Cin;
    float mu0 = 0.f, mu1 = 0.f, s0a = 0.f, s1a = 0.f, q = 0.f;
    for (int ci = 0; ci < Cin; ci += 4) {
        float4 m = *(const float4*)(mp + ci);
        float4 s = *(const float4*)(sp + ci);
        float4 wa = *(const float4*)(w_mu + ci * 2);
        float4 wb = *(const float4*)(w_mu + ci * 2 + 4);
        mu0 += m.x * wa.x + m.y * wa.z + m.z * wb.x + m.w * wb.z;
        mu1 += m.x * wa.y + m.y * wa.w + m.z * wb.y + m.w * wb.w;
        s0a += s.x * (wa.x * wa.x) + s.y * (wa.z * wa.z) + s.z * (wb.x * wb.x) + s.w * (wb.z * wb.z);
        s1a += s.x * (wa.y * wa.y) + s.y * (wa.w * wa.w) + s.z * (wb.y * wb.y) + s.w * (wb.w * wb.w);
        q += m.x * m.x + s.x + m.y * m.y + s.y + m.z * m.z + s.z + m.w * m.w + s.w;
    }
    float s0 = q * softplus_f(w_sig[0]) + s0a;
    float s1 = q * softplus_f(w_sig[1]) + s1a;
    float mx = fmaxf(mu0, mu1);
    float e0 = expf(mu0 - mx), e1 = expf(mu1 - mx);
    float inv = 1.f / (e0 + e1);
    float p0 = e0 * inv, p1 = e1 * inv;
    float g00 = p0 - p0 * p0, g01 = -p0 * p1;
    float g10 = -p1 * p0,     g11 = p1 - p1 * p1;
    float so0 = g00 * g00 * s0 + g01 * g01 * s1;
    float so1 = g10 * g10 * s0 + g11 * g11 * s1;
    out[(size_t)pix * 2]     = p0;
    out[(size_t)pix * 2 + 1] = p1;
    size_t off = (size_t)total * 2;
    out[off + (size_t)pix * 2]     = so0;
    out[off + (size_t)pix * 2 + 1] = so1;
}

// ---------------------------------------------------------------------------

extern "C" void kernel_launch(void* const* d_in, const int* in_sizes, int n_in,
                              void* d_out, int out_size, void* d_ws, size_t ws_size,
                              hipStream_t stream)
{
    const float* x = (const float*)d_in[0];
    enum { E1A, E1B, E2A, E2B, BA, BB, D2U, D2A, D2B, D1U, D1A, D1B, FIN, NW };
    const float* wmu[NW];
    const float* wsig[NW];
    for (int i = 0; i < NW; i++) {
        wmu[i]  = (const float*)d_in[1 + 2 * i];
        wsig[i] = (const float*)d_in[2 + 2 * i];
    }

    const int B_ = 4;
    float* ws = (float*)d_ws;
    float* M0  = ws;                         // 4194304 fp32 mu scratch
    float* SF  = ws + 4194304;               // 4194304 fp32 s scratch
    float* tq  = ws + 8388608;               // 65536
    float* q9  = ws + 8454144;               // 65536
    float* spb = ws + 8519680;               // 2048
    unsigned short* us = (unsigned short*)(ws + 8521728);
    const size_t NB = 4194304;
    unsigned short* aMh = us;                // A set
    unsigned short* aMl = us + NB;
    unsigned short* aSh = us + 2 * NB;
    unsigned short* aSl = us + 3 * NB;
    unsigned short* bMh = us + 4 * NB;       // B set
    unsigned short* bMl = us + 5 * NB;
    unsigned short* bSh = us + 6 * NB;
    unsigned short* bSl = us + 7 * NB;
    unsigned short* e1Mh = us + 8 * NB;      // E1 skip
    unsigned short* e1Ml = us + 9 * NB;
    unsigned short* e1Sh = us + 10 * NB;
    unsigned short* e1Sl = us + 11 * NB;
    unsigned short* e2Mh = us + 12 * NB;     // E2 skip (2097152 each)
    unsigned short* e2Ml = e2Mh + 2097152;
    unsigned short* e2Sh = e2Ml + 2097152;
    unsigned short* e2Sl = e2Sh + 2097152;
    unsigned short* wTh  = e2Sl + 2097152;   // 1695744 each (9 MFMA layers)
    unsigned short* wTl  = wTh + 1695744;
    unsigned short* wTsq = wTl + 1695744;

    // 9 dense conv layers on MFMA
    const int mlay[9]  = {E1B, E2A, E2B, BA, BB, D2A, D2B, D1A, D1B};
    const int mcin[9]  = {64, 64, 128, 128, 256, 256, 128, 128, 64};
    const int mcout[9] = {64, 128, 128, 256, 256, 128, 128, 64, 64};
    size_t woff[NW]; int spoff[NW];
    {
        size_t wo = 0; int so = 0;
        for (int i = 0; i < 9; i++) {
            int l = mlay[i];
            woff[l] = wo; spoff[l] = so;
            int n = 9 * mcin[i] * mcout[i];
            wprep3_kernel<<<dim3((n + 255) / 256), dim3(256), 0, stream>>>(
                wmu[l], wTh + wo, wTl + wo, wTsq + wo, mcin[i], mcout[i], n);
            sp_kernel<<<dim3(1), dim3(256), 0, stream>>>(wsig[l], spb + so, mcout[i]);
            wo += n; so += mcout[i];
        }
    }

    // dense fused MFMA layer: t_hl + q9 + fused conv (XCD-swizzled 1D grid)
    auto flayer = [&](const unsigned short* i_mh, const unsigned short* i_ml,
                      const unsigned short* i_sh, const unsigned short* i_sl, int ci1,
                      const unsigned short* k_mh, const unsigned short* k_ml,
                      const unsigned short* k_sh, const unsigned short* k_sl,
                      int ci2, int h2, int w2, int dh, int dw,
                      int H, int W, int widx, int cout,
                      float* oMf, float* oSf,
                      unsigned short* oMh, unsigned short* oMl,
                      unsigned short* oSh, unsigned short* oSl) {
        int total = B_ * H * W;
        t_hl_kernel<<<dim3((total + 255) / 256), dim3(256), 0, stream>>>(
            i_mh, i_ml, i_sh, i_sl, k_mh, k_ml, k_sh, k_sl, tq,
            B_, H, W, ci1, ci2, h2, w2, dh, dw);
        q9_kernel<<<dim3((total + 255) / 256), dim3(256), 0, stream>>>(tq, q9, B_, H, W);
        int nReal = ((total + 63) / 64) * (cout / 64);
        int G = ((nReal + 7) / 8) * 8;
        fused_layer_kernel<<<dim3(G), dim3(256), 0, stream>>>(
            i_mh, i_ml, i_sh, i_sl, k_mh, k_ml, k_sh, k_sl, q9,
            wTh + woff[widx], wTl + woff[widx], wTsq + woff[widx], spb + spoff[widx],
            oMf, oSf, oMh, oMl, oSh, oSl,
            B_, H, W, ci1, ci2, h2, w2, dh, dw, cout);
    };

    // vector unpool layer (exact fp32 gates), pair-blocked
    auto unpool = [&](const float* mi, const float* si,
                      int hi, int wi, int ci, int ho, int wo, int co, int widx,
                      unsigned short* oMh, unsigned short* oMl,
                      unsigned short* oSh, unsigned short* oSl) {
        int nin = B_ * hi * wi;
        t_f32_kernel<<<dim3((nin + 255) / 256), dim3(256), 0, stream>>>(mi, si, tq, nin, ci);
        int Wp = 2 * ((wo + 3) / 4);
        int totalP = B_ * ho * Wp;
        int tx = co / 4, ty = 256 / tx;
        conv_unpool_pair<<<dim3((totalP + ty - 1) / ty), dim3(tx, ty), 0, stream>>>(
            mi, si, tq, wmu[widx], wsig[widx], oMh, oMl, oSh, oSl,
            B_, hi, wi, ci, ho, wo, co);
    };

    // ---- encoder level 1 ----
    {
        int totalPix = B_ * 128 * 128;
        conv_input_relu_kernel<<<dim3((totalPix + 3) / 4), dim3(64, 4), 0, stream>>>(
            x, wmu[E1A], wsig[E1A], aMh, aMl, aSh, aSl, B_, 128, 128, 3, 64);
    }
    // E1B: A -> E1 skip (hi/lo) + fp32 mu (M0) for pool argmax
    flayer(aMh, aMl, aSh, aSl, 64, nullptr, nullptr, nullptr, nullptr, 0, 0, 0, 0, 0,
           128, 128, E1B, 64, M0, nullptr, e1Mh, e1Ml, e1Sh, e1Sl);
    {
        size_t total = (size_t)B_ * 64 * 64 * 64;
        pool_kernel<<<dim3((total + 255) / 256), dim3(256), 0, stream>>>(
            M0, e1Sh, e1Sl, bMh, bMl, bSh, bSl, B_, 128, 128, 64);
    }
    // ---- encoder level 2 ----
    flayer(bMh, bMl, bSh, bSl, 64, nullptr, nullptr, nullptr, nullptr, 0, 0, 0, 0, 0,
           64, 64, E2A, 128, nullptr, nullptr, aMh, aMl, aSh, aSl);
    flayer(aMh, aMl, aSh, aSl, 128, nullptr, nullptr, nullptr, nullptr, 0, 0, 0, 0, 0,
           64, 64, E2B, 128, M0, nullptr, e2Mh, e2Ml, e2Sh, e2Sl);
    {
        size_t total = (size_t)B_ * 32 * 32 * 128;
        pool_kernel<<<dim3((total + 255) / 256), dim3(256), 0, stream>>>(
            M0, e2Sh, e2Sl, bMh, bMl, bSh, bSl, B_, 64, 64, 128);
    }
    // ---- bottleneck ----
    flayer(bMh, bMl, bSh, bSl, 128, nullptr, nullptr, nullptr, nullptr, 0, 0, 0, 0, 0,
           32, 32, BA, 256, nullptr, nullptr, aMh, aMl, aSh, aSl);
    flayer(aMh, aMl, aSh, aSl, 256, nullptr, nullptr, nullptr, nullptr, 0, 0, 0, 0, 0,
           32, 32, BB, 256, M0, SF, nullptr, nullptr, nullptr, nullptr);
    // ---- decoder level 2 ----
    unpool(M0, SF, 32, 32, 256, 63, 63, 128, D2U, bMh, bMl, bSh, bSl);
    flayer(bMh, bMl, bSh, bSl, 128, e2Mh, e2Ml, e2Sh, e2Sl, 128, 64, 64, 0, 0,
           63, 63, D2A, 128, nullptr, nullptr, aMh, aMl, aSh, aSl);
    flayer(aMh, aMl, aSh, aSl, 128, nullptr, nullptr, nullptr, nullptr, 0, 0, 0, 0, 0,
           63, 63, D2B, 128, M0, SF, nullptr, nullptr, nullptr, nullptr);
    // ---- decoder level 1 ----
    unpool(M0, SF, 63, 63, 128, 125, 125, 64, D1U, bMh, bMl, bSh, bSl);
    flayer(bMh, bMl, bSh, bSl, 64, e1Mh, e1Ml, e1Sh, e1Sl, 64, 128, 128, 1, 1,
           125, 125, D1A, 64, nullptr, nullptr, aMh, aMl, aSh, aSl);
    flayer(aMh, aMl, aSh, aSl, 64, nullptr, nullptr, nullptr, nullptr, 0, 0, 0, 0, 0,
           125, 125, D1B, 64, M0, SF, nullptr, nullptr, nullptr, nullptr);
    // ---- final 1x1 + softmax prop ----
    {
        int totalPix = B_ * 125 * 125;
        final_kernel<<<dim3((totalPix + 63) / 64), dim3(64), 0, stream>>>(
            M0, SF, wmu[FIN], wsig[FIN], (float*)d_out, B_, 125, 125, 64);
    }
}